// Round 2
// baseline (76443.079 us; speedup 1.0000x reference)
//
#include <hip/hip_runtime.h>

// Problem constants
#define N_MEL 80
#define ENC   512
#define ARNN  1024
#define PRE   256
#define ADIM  128
#define NFILT 32
#define KS    31
#define BSZ   16
#define TENC  128
#define TDEC  128

// Workspace layout (float offsets)
#define OFF_XA     0u          // [128][16][4096] precomputed x@Wih_x^T + bih + bhh
#define OFF_X      8388608u    // [128][16][256]  prenet out
#define OFF_H1     8912896u    // [128][16][256]  prenet hidden
#define OFF_DECIN  9437184u    // [128][16][80]
#define OFF_PM     9601024u    // [16][128][128]  processed memory
#define OFF_ATTNH  9863168u    // [2][16][1024]
#define OFF_ATTNC  9895936u    // [16][1024]
#define OFF_DECH   9912320u    // [2][16][1024]
#define OFF_DECC   9945088u    // [16][1024]
#define OFF_CTX    9961472u    // [2][16][512]
#define OFF_AW     9977856u    // [2][16][128]
#define OFF_AWC    9981952u    // [2][16][128]
#define STATE_FLOATS 122880    // from OFF_ATTNH to end of AWC
#define OFF_BAR    (OFF_ATTNH + STATE_FLOATS)   // barrier counter (1 word, zeroed)

__device__ __forceinline__ float sigmf(float x) { return 1.0f / (1.0f + __expf(-x)); }
__device__ __forceinline__ float tanhfast(float x) { return 1.0f - 2.0f / (__expf(2.0f * x) + 1.0f); }

// ---------------- precompute kernels ----------------

__global__ void __launch_bounds__(1024) build_decin(const float* __restrict__ mels,
                                                    float* __restrict__ decin) {
    int idx = blockIdx.x * 1024 + threadIdx.x;  // 128*16*80 = 163840
    if (idx >= 128 * 16 * 80) return;
    int t = idx / 1280, r = idx % 1280;
    int b = r / 80, m = r % 80;
    decin[idx] = (t == 0) ? 0.f : mels[b * (80 * 128) + m * 128 + (t - 1)];
}

// C[M][N] = act(A[M][K] @ B[N][K]^T + bias1 + bias2); M,N multiples of 64.
__global__ void __launch_bounds__(256) gemm_kernel(
    const float* __restrict__ A, int lda,
    const float* __restrict__ B, int ldb,
    float* __restrict__ C, int ldc,
    int M, int N, int K,
    const float* __restrict__ bias1, const float* __restrict__ bias2, int relu) {
    __shared__ float As[16][68];
    __shared__ float Bs[16][68];
    int tid = threadIdx.x;
    int tn = tid & 15, tm = tid >> 4;
    int m0 = blockIdx.y * 64, n0 = blockIdx.x * 64;
    float acc[4][4] = {};
    for (int k0 = 0; k0 < K; k0 += 16) {
        for (int idx = tid; idx < 1024; idx += 256) {
            int mm = idx >> 4, kk = idx & 15;
            int kg = k0 + kk;
            As[kk][mm] = (kg < K) ? A[(size_t)(m0 + mm) * lda + kg] : 0.f;
            Bs[kk][mm] = (kg < K) ? B[(size_t)(n0 + mm) * ldb + kg] : 0.f;
        }
        __syncthreads();
#pragma unroll
        for (int kk = 0; kk < 16; kk++) {
            float av[4], bv[4];
#pragma unroll
            for (int i = 0; i < 4; i++) { av[i] = As[kk][tm * 4 + i]; bv[i] = Bs[kk][tn * 4 + i]; }
#pragma unroll
            for (int i = 0; i < 4; i++)
#pragma unroll
                for (int j = 0; j < 4; j++) acc[i][j] += av[i] * bv[j];
        }
        __syncthreads();
    }
    for (int i = 0; i < 4; i++) {
        int m = m0 + tm * 4 + i;
        for (int j = 0; j < 4; j++) {
            int n = n0 + tn * 4 + j;
            float v = acc[i][j];
            if (bias1) v += bias1[n];
            if (bias2) v += bias2[n];
            if (relu) v = fmaxf(v, 0.f);
            C[(size_t)m * ldc + n] = v;
        }
    }
}

// ---------------- main persistent cooperative kernel ----------------

struct DecArgs {
    const float* memory;
    const int* memlen;
    const float* arnn_wih;
    const float* arnn_whh;
    const float* drnn_wih;
    const float* drnn_whh;
    const float* drnn_bih;
    const float* drnn_bhh;
    const float* query_w;
    const float* v_w;
    const float* conv_w;
    const float* dense_w;
    const float* proj_w;
    const float* proj_b;
    const float* gate_w;
    const float* gate_b;
    float* ws;
    float* out;
};

// Lightweight grid barrier: monotonic counter in device memory (zeroed by
// hipMemsetAsync before launch). Release fence -> arrive -> lead spin ->
// acquire fence. Mirrors cg::grid.sync coherence semantics at lower cost.
__device__ __forceinline__ void gridbar(unsigned* bar, unsigned target) {
    __syncthreads();
    __threadfence();   // release: drain this block's writes past per-XCD L2
    if (threadIdx.x == 0) {
        atomicAdd(bar, 1u);
        while (__hip_atomic_load(bar, __ATOMIC_RELAXED, __HIP_MEMORY_SCOPE_AGENT) < target) {
            __builtin_amdgcn_s_sleep(2);
        }
    }
    __syncthreads();
    __threadfence();   // acquire: invalidate stale cached state
}

__global__ void __launch_bounds__(1024, 4) decoder_main(DecArgs A) {
    const int tid = threadIdx.x;
    const int wv = tid >> 6;
    const int lane = tid & 63;
    const int blk = blockIdx.x;
    float* ws = A.ws;
    unsigned* bar = (unsigned*)(ws + OFF_BAR);

    // LDS
    __shared__ alignas(16) float s_in[11264];   // 44KB input staging (4-batch groups)
    __shared__ float s_part[1024];              // [16b][16row][4kg] partials
    __shared__ float s_ah[1024];
    __shared__ float s_loc[128 * 33];
    __shared__ float s_pq[128];
    __shared__ float s_ev[128];
    __shared__ float s_aw2[128];
    __shared__ float s_awl[128];
    __shared__ float s_awcl[128];
    __shared__ float s_ep[1024];
    __shared__ float s_red[2];

    // thread layout for LSTM phases:
    // wave = kg*4 + gate ; lane = k16*4 + unit
    const int kg = wv >> 2;      // K-group [0,4)
    const int gate = wv & 3;     // gate (i,f,g,o)
    const int k16 = lane >> 2;   // K-sub [0,16)
    const int r = lane & 3;      // unit within block [0,4)
    const int sid = kg * 16 + k16;          // K-slice id [0,64)
    const int jrow = blk * 4 + r;           // hidden-unit index [0,1024)
    const int arow = gate * 1024 + jrow;    // row in the 4096-row gate matrices

    // ---- load register-resident weights (once per call) ----
    float4 wa[6];    // attn LSTM: K order [ctx(512) | attn_h(1024)], 24 floats
    {
        const float* wihrow = A.arnn_wih + (size_t)arow * 768 + 256;  // ctx cols
        const float* whhrow = A.arnn_whh + (size_t)arow * 1024;
#pragma unroll
        for (int i = 0; i < 6; i++) {
            int k = sid * 24 + i * 4;   // 512 % 4 == 0 -> no float4 straddle
            const float* p = (k < 512) ? (wihrow + k) : (whhrow + (k - 512));
            wa[i] = *reinterpret_cast<const float4*>(p);
        }
    }
    float4 wd[10];   // dec LSTM: K order [attn_h(1024) | ctx(512) | dec_h(1024)], 40 floats
    {
        const float* wihrow = A.drnn_wih + (size_t)arow * 1536;
        const float* whhrow = A.drnn_whh + (size_t)arow * 1024;
#pragma unroll
        for (int i = 0; i < 10; i++) {
            int k = sid * 40 + i * 4;   // 1536 % 4 == 0 -> no straddle
            const float* p = (k < 1536) ? (wihrow + k) : (whhrow + (k - 1536));
            wd[i] = *reinterpret_cast<const float4*>(p);
        }
    }

    unsigned bt = 0;   // barrier target

    // ---- LSTM phase: register weights x LDS-staged inputs ----
    // isD=0: attn (K=1536, 6 f4, slice stride 28); isD=1: dec (K=2560, 10 f4, stride 44)
    auto lstm_phase = [&](int isD, int t, int wpar, int rpar) {
        const int K = isD ? 2560 : 1536;
        const int NS = isD ? 44 : 28;        // padded slice stride (floats)
        const int BS = isD ? 2816 : 1792;    // per-batch buffer (64*NS)
        for (int g4 = 0; g4 < 4; ++g4) {
            __syncthreads();
            // stage 4 batches of the input vector
            for (int bb4 = 0; bb4 < 4; ++bb4) {
                int b = g4 * 4 + bb4;
                const float* ctx = ws + OFF_CTX + (isD ? wpar : rpar) * 8192 + b * 512;
                const float* ah  = ws + OFF_ATTNH + (isD ? wpar : rpar) * 16384 + b * 1024;
                const float* dh  = ws + OFF_DECH + rpar * 16384 + b * 1024;
                for (int k = tid; k < K; k += 1024) {
                    float v;
                    if (!isD) v = (k < 512) ? ctx[k] : ah[k - 512];
                    else      v = (k < 1024) ? ah[k] : ((k < 1536) ? ctx[k - 1024] : dh[k - 1536]);
                    int q = isD ? (k / 40) : (k / 24);
                    int rem = isD ? (k - q * 40) : (k - q * 24);
                    s_in[bb4 * BS + q * NS + rem] = v;
                }
            }
            __syncthreads();
#pragma unroll
            for (int bb4 = 0; bb4 < 4; ++bb4) {
                const float* xin = s_in + bb4 * BS + sid * NS;
                float a = 0.f;
                if (!isD) {
#pragma unroll
                    for (int i = 0; i < 6; i++) {
                        float4 x = *reinterpret_cast<const float4*>(xin + i * 4);
                        a += wa[i].x * x.x + wa[i].y * x.y + wa[i].z * x.z + wa[i].w * x.w;
                    }
                } else {
#pragma unroll
                    for (int i = 0; i < 10; i++) {
                        float4 x = *reinterpret_cast<const float4*>(xin + i * 4);
                        a += wd[i].x * x.x + wd[i].y * x.y + wd[i].z * x.z + wd[i].w * x.w;
                    }
                }
                a += __shfl_xor(a, 4);
                a += __shfl_xor(a, 8);
                a += __shfl_xor(a, 16);
                a += __shfl_xor(a, 32);
                if (k16 == 0) {
                    int b = g4 * 4 + bb4;
                    s_part[(b * 16 + gate * 4 + r) * 4 + kg] = a;
                }
            }
        }
        __syncthreads();
        // finalize: 64 threads, one per (batch, unit)
        if (tid < 64) {
            int b = tid >> 2, u = tid & 3;
            float G[4];
#pragma unroll
            for (int g = 0; g < 4; g++) {
                const float* pp = s_part + (b * 16 + g * 4 + u) * 4;
                G[g] = pp[0] + pp[1] + pp[2] + pp[3];
            }
            int j = blk * 4 + u;
            float* Cst; float* Hst;
            if (!isD) {
                const float* xa = ws + OFF_XA + (size_t)(t * 16 + b) * 4096;
                G[0] += xa[j]; G[1] += xa[1024 + j]; G[2] += xa[2048 + j]; G[3] += xa[3072 + j];
                Cst = ws + OFF_ATTNC; Hst = ws + OFF_ATTNH + wpar * 16384;
            } else {
                G[0] += A.drnn_bih[j] + A.drnn_bhh[j];
                G[1] += A.drnn_bih[1024 + j] + A.drnn_bhh[1024 + j];
                G[2] += A.drnn_bih[2048 + j] + A.drnn_bhh[2048 + j];
                G[3] += A.drnn_bih[3072 + j] + A.drnn_bhh[3072 + j];
                Cst = ws + OFF_DECC; Hst = ws + OFF_DECH + wpar * 16384;
            }
            float ig = sigmf(G[0]), fg = sigmf(G[1]), gg = tanhfast(G[2]), og = sigmf(G[3]);
            float c = fg * Cst[b * 1024 + j] + ig * gg;
            Cst[b * 1024 + j] = c;
            Hst[b * 1024 + j] = og * tanhfast(c);
        }
    };

    auto attention = [&](int t, int wpar, int rpar) {
        const int b = blk;
        s_ah[tid] = ws[OFF_ATTNH + wpar * 16384 + b * 1024 + tid];
        if (tid < 128) {
            s_awl[tid] = ws[OFF_AW + rpar * 2048 + b * 128 + tid];
            s_awcl[tid] = ws[OFF_AWC + rpar * 2048 + b * 128 + tid];
        }
        __syncthreads();
        for (int idx = tid; idx < 4096; idx += 1024) {
            int f = idx >> 7, tt = idx & 127;
            const float* w0 = A.conv_w + f * 62;
            float s = 0.f;
#pragma unroll
            for (int k = 0; k < 31; k++) {
                int j = tt + k - 15;
                if (j >= 0 && j < 128) s += w0[k] * s_awl[j] + w0[31 + k] * s_awcl[j];
            }
            s_loc[tt * 33 + f] = s;
        }
        {
#pragma unroll
            for (int ii = 0; ii < 8; ii++) {
                int a = wv * 8 + ii;
                const float* qw = A.query_w + a * 1024;
                float s = 0.f;
#pragma unroll
                for (int q = 0; q < 4; q++) {
                    int k = q * 256 + lane * 4;
                    float4 h4 = *reinterpret_cast<const float4*>(&s_ah[k]);
                    float4 w4 = *reinterpret_cast<const float4*>(&qw[k]);
                    s += h4.x * w4.x + h4.y * w4.y + h4.z * w4.z + h4.w * w4.w;
                }
#pragma unroll
                for (int off = 1; off < 64; off <<= 1) s += __shfl_xor(s, off);
                if (lane == 0) s_pq[a] = s;
            }
        }
        __syncthreads();
        {
            int tt = tid >> 3, sl = tid & 7;
            float part = 0.f;
            for (int i = 0; i < 16; i++) {
                int a = i * 8 + sl;
                float lp = 0.f;
                const float* dw = A.dense_w + a * 32;
#pragma unroll
                for (int f = 0; f < 32; f++) lp += s_loc[tt * 33 + f] * dw[f];
                float arg = s_pq[a] + lp + ws[OFF_PM + (b * 128 + tt) * 128 + a];
                part += A.v_w[a] * tanhfast(arg);
            }
            s_ep[tid] = part;
        }
        __syncthreads();
        int ml = A.memlen[b];
        if (tid < 128) {
            float s = 0.f;
#pragma unroll
            for (int q = 0; q < 8; q++) s += s_ep[tid * 8 + q];
            if (tid >= ml) s = -1e30f;
            s_ev[tid] = s;
        }
        __syncthreads();
        if (wv == 0) {
            float m = fmaxf(s_ev[lane], s_ev[lane + 64]);
#pragma unroll
            for (int off = 1; off < 64; off <<= 1) m = fmaxf(m, __shfl_xor(m, off));
            if (lane == 0) s_red[0] = m;
        }
        __syncthreads();
        if (tid < 128) s_aw2[tid] = __expf(s_ev[tid] - s_red[0]);
        __syncthreads();
        if (wv == 0) {
            float s = s_aw2[lane] + s_aw2[lane + 64];
#pragma unroll
            for (int off = 1; off < 64; off <<= 1) s += __shfl_xor(s, off);
            if (lane == 0) s_red[1] = 1.f / s;
        }
        __syncthreads();
        if (tid < 128) {
            float val = s_aw2[tid] * s_red[1];
            s_aw2[tid] = val;
            ws[OFF_AW + wpar * 2048 + b * 128 + tid] = val;
            ws[OFF_AWC + wpar * 2048 + b * 128 + tid] = s_awcl[tid] + val;
            A.out[165888 + b * 16384 + t * 128 + tid] = val;  // alignments
        }
        __syncthreads();
        if (tid < 512) {
            const float* mb = A.memory + (size_t)b * 65536 + tid;
            float acc = 0.f;
            for (int tt2 = 0; tt2 < 128; tt2++) acc += s_aw2[tt2] * mb[tt2 * 512];
            ws[OFF_CTX + wpar * 8192 + b * 512 + tid] = acc;
        }
    };

    auto eout = [&](int tdone) {
        int widx = (blk - 16) * 16 + wv;
        if (widx >= 1296) return;
        int ppar = tdone & 1;
        int b; const float* wrow; float bias; float* dst;
        if (widx < 1280) {
            b = widx / 80; int m = widx % 80;
            wrow = A.proj_w + m * 1536; bias = A.proj_b[m];
            dst = A.out + (size_t)(b * 80 + m) * 128 + tdone;
        } else {
            b = widx - 1280;
            wrow = A.gate_w; bias = A.gate_b[0];
            dst = A.out + 163840 + b * 128 + tdone;
        }
        const float* h1p = ws + OFF_DECH + ppar * 16384 + b * 1024;
        const float* c1p = ws + OFF_CTX + ppar * 8192 + b * 512;
        float s = 0.f;
#pragma unroll
        for (int q = 0; q < 6; q++) {
            int k = q * 256 + lane * 4;
            float4 w4 = *reinterpret_cast<const float4*>(&wrow[k]);
            float4 h4;
            if (k < 1024) h4 = *reinterpret_cast<const float4*>(&h1p[k]);
            else h4 = *reinterpret_cast<const float4*>(&c1p[k - 1024]);
            s += w4.x * h4.x + w4.y * h4.y + w4.z * h4.z + w4.w * h4.w;
        }
#pragma unroll
        for (int off = 1; off < 64; off <<= 1) s += __shfl_xor(s, off);
        if (lane == 0) *dst = s + bias;
    };

    for (int t = 0; t < 128; t++) {
        int wpar = t & 1, rpar = wpar ^ 1;
        lstm_phase(0, t, wpar, rpar);                 // attn LSTM
        bt += 256; gridbar(bar, bt);
        if (blk < 16) attention(t, wpar, rpar);
        else if (t >= 1) eout(t - 1);
        bt += 256; gridbar(bar, bt);
        lstm_phase(1, t, wpar, rpar);                 // dec LSTM
        bt += 256; gridbar(bar, bt);
    }
    if (blk >= 16) eout(127);
}

// ---------------- launcher ----------------

extern "C" void kernel_launch(void* const* d_in, const int* in_sizes, int n_in,
                              void* d_out, int out_size, void* d_ws, size_t ws_size,
                              hipStream_t stream) {
    (void)in_sizes; (void)n_in; (void)out_size; (void)ws_size;
    const float* memory    = (const float*)d_in[0];
    const float* mels      = (const float*)d_in[1];
    const int*   memlen    = (const int*)d_in[2];
    const float* prenet_w1 = (const float*)d_in[3];
    const float* prenet_w2 = (const float*)d_in[4];
    const float* arnn_wih  = (const float*)d_in[5];
    const float* arnn_whh  = (const float*)d_in[6];
    const float* arnn_bih  = (const float*)d_in[7];
    const float* arnn_bhh  = (const float*)d_in[8];
    const float* query_w   = (const float*)d_in[9];
    const float* memory_w  = (const float*)d_in[10];
    const float* v_w       = (const float*)d_in[11];
    const float* conv_w    = (const float*)d_in[12];
    const float* dense_w   = (const float*)d_in[13];
    const float* drnn_wih  = (const float*)d_in[14];
    const float* drnn_whh  = (const float*)d_in[15];
    const float* drnn_bih  = (const float*)d_in[16];
    const float* drnn_bhh  = (const float*)d_in[17];
    const float* proj_w    = (const float*)d_in[18];
    const float* proj_b    = (const float*)d_in[19];
    const float* gate_w    = (const float*)d_in[20];
    const float* gate_b    = (const float*)d_in[21];
    float* ws = (float*)d_ws;
    float* out = (float*)d_out;

    // zero recurrent state + barrier counter (ws is poisoned 0xAA each call)
    hipMemsetAsync(ws + OFF_ATTNH, 0, (STATE_FLOATS + 16) * sizeof(float), stream);

    build_decin<<<dim3(160), dim3(1024), 0, stream>>>(mels, ws + OFF_DECIN);
    gemm_kernel<<<dim3(4, 32), dim3(256), 0, stream>>>(ws + OFF_DECIN, 80, prenet_w1, 80,
                                                       ws + OFF_H1, 256, 2048, 256, 80,
                                                       nullptr, nullptr, 1);
    gemm_kernel<<<dim3(4, 32), dim3(256), 0, stream>>>(ws + OFF_H1, 256, prenet_w2, 256,
                                                       ws + OFF_X, 256, 2048, 256, 256,
                                                       nullptr, nullptr, 1);
    gemm_kernel<<<dim3(64, 32), dim3(256), 0, stream>>>(ws + OFF_X, 256, arnn_wih, 768,
                                                        ws + OFF_XA, 4096, 2048, 4096, 256,
                                                        arnn_bih, arnn_bhh, 0);
    gemm_kernel<<<dim3(2, 32), dim3(256), 0, stream>>>(memory, 512, memory_w, 512,
                                                       ws + OFF_PM, 128, 2048, 128, 512,
                                                       nullptr, nullptr, 0);

    DecArgs a;
    a.memory = memory; a.memlen = memlen;
    a.arnn_wih = arnn_wih; a.arnn_whh = arnn_whh;
    a.drnn_wih = drnn_wih; a.drnn_whh = drnn_whh;
    a.drnn_bih = drnn_bih; a.drnn_bhh = drnn_bhh;
    a.query_w = query_w; a.v_w = v_w;
    a.conv_w = conv_w; a.dense_w = dense_w;
    a.proj_w = proj_w; a.proj_b = proj_b;
    a.gate_w = gate_w; a.gate_b = gate_b;
    a.ws = ws; a.out = out;
    void* kargs[] = { &a };
    hipLaunchCooperativeKernel((const void*)decoder_main, dim3(256), dim3(1024),
                               kargs, 0, stream);
}

// Round 4
// 54264.764 us; speedup vs baseline: 1.4087x; 1.4087x over previous
//
#include <hip/hip_runtime.h>

// Problem constants
#define N_MEL 80
#define ENC   512
#define ARNN  1024
#define PRE   256
#define ADIM  128
#define NFILT 32
#define KS    31
#define BSZ   16
#define TENC  128
#define TDEC  128

// Workspace layout (float offsets)
#define OFF_XA     0u          // [128][16][4096] precomputed x@Wih_x^T + bih + bhh
#define OFF_X      8388608u    // [128][16][256]  prenet out
#define OFF_H1     8912896u    // [128][16][256]  prenet hidden
#define OFF_DECIN  9437184u    // [128][16][80]
#define OFF_PM     9601024u    // [16][128][128]  processed memory
#define OFF_ATTNH  9863168u    // [2][16][1024]
#define OFF_ATTNC  9895936u    // [16][1024]
#define OFF_DECH   9912320u    // [2][16][1024]
#define OFF_DECC   9945088u    // [16][1024]
#define OFF_CTX    9961472u    // [2][16][512]
#define OFF_AW     9977856u    // [2][16][128]
#define OFF_AWC    9981952u    // [2][16][128]
#define STATE_FLOATS 122880    // from OFF_ATTNH to end of AWC
#define OFF_BAR    (OFF_ATTNH + STATE_FLOATS)   // barrier counter (1 word, zeroed)

__device__ __forceinline__ float sigmf(float x) { return 1.0f / (1.0f + __expf(-x)); }
__device__ __forceinline__ float tanhfast(float x) { return 1.0f - 2.0f / (__expf(2.0f * x) + 1.0f); }
__device__ __forceinline__ float dot4(float4 a, float4 b) {
    return a.x * b.x + a.y * b.y + a.z * b.z + a.w * b.w;
}

// ---------------- precompute kernels ----------------

__global__ void __launch_bounds__(1024) build_decin(const float* __restrict__ mels,
                                                    float* __restrict__ decin) {
    int idx = blockIdx.x * 1024 + threadIdx.x;  // 128*16*80 = 163840
    if (idx >= 128 * 16 * 80) return;
    int t = idx / 1280, r = idx % 1280;
    int b = r / 80, m = r % 80;
    decin[idx] = (t == 0) ? 0.f : mels[b * (80 * 128) + m * 128 + (t - 1)];
}

// C[M][N] = act(A[M][K] @ B[N][K]^T + bias1 + bias2); M,N multiples of 64.
__global__ void __launch_bounds__(256) gemm_kernel(
    const float* __restrict__ A, int lda,
    const float* __restrict__ B, int ldb,
    float* __restrict__ C, int ldc,
    int M, int N, int K,
    const float* __restrict__ bias1, const float* __restrict__ bias2, int relu) {
    __shared__ float As[16][68];
    __shared__ float Bs[16][68];
    int tid = threadIdx.x;
    int tn = tid & 15, tm = tid >> 4;
    int m0 = blockIdx.y * 64, n0 = blockIdx.x * 64;
    float acc[4][4] = {};
    for (int k0 = 0; k0 < K; k0 += 16) {
        for (int idx = tid; idx < 1024; idx += 256) {
            int mm = idx >> 4, kk = idx & 15;
            int kg = k0 + kk;
            As[kk][mm] = (kg < K) ? A[(size_t)(m0 + mm) * lda + kg] : 0.f;
            Bs[kk][mm] = (kg < K) ? B[(size_t)(n0 + mm) * ldb + kg] : 0.f;
        }
        __syncthreads();
#pragma unroll
        for (int kk = 0; kk < 16; kk++) {
            float av[4], bv[4];
#pragma unroll
            for (int i = 0; i < 4; i++) { av[i] = As[kk][tm * 4 + i]; bv[i] = Bs[kk][tn * 4 + i]; }
#pragma unroll
            for (int i = 0; i < 4; i++)
#pragma unroll
                for (int j = 0; j < 4; j++) acc[i][j] += av[i] * bv[j];
        }
        __syncthreads();
    }
    for (int i = 0; i < 4; i++) {
        int m = m0 + tm * 4 + i;
        for (int j = 0; j < 4; j++) {
            int n = n0 + tn * 4 + j;
            float v = acc[i][j];
            if (bias1) v += bias1[n];
            if (bias2) v += bias2[n];
            if (relu) v = fmaxf(v, 0.f);
            C[(size_t)m * ldc + n] = v;
        }
    }
}

// ---------------- main persistent cooperative kernel ----------------

struct DecArgs {
    const float* memory;
    const int* memlen;
    const float* arnn_wih;
    const float* arnn_whh;
    const float* drnn_wih;
    const float* drnn_whh;
    const float* drnn_bih;
    const float* drnn_bhh;
    const float* query_w;
    const float* v_w;
    const float* conv_w;
    const float* dense_w;
    const float* proj_w;
    const float* proj_b;
    const float* gate_w;
    const float* gate_b;
    float* ws;
    float* out;
};

// Lightweight grid barrier: monotonic counter in device memory (zeroed before
// launch). Release fence -> arrive -> lead spin -> acquire fence.
__device__ __forceinline__ void gridbar(unsigned* bar, unsigned target) {
    __syncthreads();
    __threadfence();   // release
    if (threadIdx.x == 0) {
        atomicAdd(bar, 1u);
        while (__hip_atomic_load(bar, __ATOMIC_RELAXED, __HIP_MEMORY_SCOPE_AGENT) < target) {
            __builtin_amdgcn_s_sleep(2);
        }
    }
    __syncthreads();
    __threadfence();   // acquire
}

// Attention LSTM for step t: weights passed BY VALUE (registers), no arrays.
__device__ __forceinline__ void attn_lstm_phase(
    const DecArgs& A, float* ws, float* s_in, float* s_part,
    int tid, int kg, int gate, int k16, int r, int blk, int t, int wp, int rp,
    float4 wa0, float4 wa1, float4 wa2, float4 wa3, float4 wa4, float4 wa5) {
    const int sid4 = (kg * 16 + k16) * 4;
    for (int g4 = 0; g4 < 4; ++g4) {
        __syncthreads();
#pragma unroll
        for (int bb4 = 0; bb4 < 4; ++bb4) {
            int b = g4 * 4 + bb4;
            const float* ctx = ws + OFF_CTX + rp * 8192 + b * 512;
            const float* ah  = ws + OFF_ATTNH + rp * 16384 + b * 1024;
            float* dst = s_in + bb4 * 1536;
            dst[tid] = (tid < 512) ? ctx[tid] : ah[tid - 512];
            if (tid < 512) dst[1024 + tid] = ah[512 + tid];
        }
        __syncthreads();
#pragma unroll
        for (int bb4 = 0; bb4 < 4; ++bb4) {
            const float* xp = s_in + bb4 * 1536 + sid4;
            float4 x0 = *(const float4*)(xp);
            float4 x1 = *(const float4*)(xp + 256);
            float4 x2 = *(const float4*)(xp + 512);
            float4 x3 = *(const float4*)(xp + 768);
            float4 x4 = *(const float4*)(xp + 1024);
            float4 x5 = *(const float4*)(xp + 1280);
            float a = dot4(wa0, x0) + dot4(wa1, x1) + dot4(wa2, x2)
                    + dot4(wa3, x3) + dot4(wa4, x4) + dot4(wa5, x5);
            a += __shfl_xor(a, 4);
            a += __shfl_xor(a, 8);
            a += __shfl_xor(a, 16);
            a += __shfl_xor(a, 32);
            if (k16 == 0) s_part[((g4 * 4 + bb4) * 16 + gate * 4 + r) * 4 + kg] = a;
        }
    }
    __syncthreads();
    if (tid < 64) {
        int b = tid >> 2, u = tid & 3;
        float G0 = 0.f, G1 = 0.f, G2 = 0.f, G3 = 0.f;
        const float* pp = s_part + b * 64 + u * 4;
#pragma unroll
        for (int k = 0; k < 4; k++) {
            G0 += pp[0 * 16 + k]; G1 += pp[1 * 16 + k];
            G2 += pp[2 * 16 + k]; G3 += pp[3 * 16 + k];
        }
        int j = blk * 4 + u;
        const float* xa = ws + OFF_XA + (size_t)(t * 16 + b) * 4096;
        G0 += xa[j]; G1 += xa[1024 + j]; G2 += xa[2048 + j]; G3 += xa[3072 + j];
        float ig = sigmf(G0), fg = sigmf(G1), gg = tanhfast(G2), og = sigmf(G3);
        float c = fg * ws[OFF_ATTNC + b * 1024 + j] + ig * gg;
        ws[OFF_ATTNC + b * 1024 + j] = c;
        ws[OFF_ATTNH + wp * 16384 + b * 1024 + j] = og * tanhfast(c);
    }
}

// Decoder LSTM for step t.
__device__ __forceinline__ void dec_lstm_phase(
    const DecArgs& A, float* ws, float* s_in, float* s_part,
    int tid, int kg, int gate, int k16, int r, int blk, int wp, int rp,
    float4 wd0, float4 wd1, float4 wd2, float4 wd3, float4 wd4,
    float4 wd5, float4 wd6, float4 wd7, float4 wd8, float4 wd9) {
    const int sid4 = (kg * 16 + k16) * 4;
    for (int g4 = 0; g4 < 4; ++g4) {
        __syncthreads();
#pragma unroll
        for (int bb4 = 0; bb4 < 4; ++bb4) {
            int b = g4 * 4 + bb4;
            const float* ah  = ws + OFF_ATTNH + wp * 16384 + b * 1024;
            const float* ctx = ws + OFF_CTX + wp * 8192 + b * 512;
            const float* dh  = ws + OFF_DECH + rp * 16384 + b * 1024;
            float* dst = s_in + bb4 * 2560;
            dst[tid] = ah[tid];
            dst[1024 + tid] = (tid < 512) ? ctx[tid] : dh[tid - 512];
            if (tid < 512) dst[2048 + tid] = dh[512 + tid];
        }
        __syncthreads();
#pragma unroll
        for (int bb4 = 0; bb4 < 4; ++bb4) {
            const float* xp = s_in + bb4 * 2560 + sid4;
            float a;
            {
                float4 x0 = *(const float4*)(xp);
                float4 x1 = *(const float4*)(xp + 256);
                float4 x2 = *(const float4*)(xp + 512);
                float4 x3 = *(const float4*)(xp + 768);
                float4 x4 = *(const float4*)(xp + 1024);
                a = dot4(wd0, x0) + dot4(wd1, x1) + dot4(wd2, x2)
                  + dot4(wd3, x3) + dot4(wd4, x4);
            }
            {
                float4 x5 = *(const float4*)(xp + 1280);
                float4 x6 = *(const float4*)(xp + 1536);
                float4 x7 = *(const float4*)(xp + 1792);
                float4 x8 = *(const float4*)(xp + 2048);
                float4 x9 = *(const float4*)(xp + 2304);
                a += dot4(wd5, x5) + dot4(wd6, x6) + dot4(wd7, x7)
                   + dot4(wd8, x8) + dot4(wd9, x9);
            }
            a += __shfl_xor(a, 4);
            a += __shfl_xor(a, 8);
            a += __shfl_xor(a, 16);
            a += __shfl_xor(a, 32);
            if (k16 == 0) s_part[((g4 * 4 + bb4) * 16 + gate * 4 + r) * 4 + kg] = a;
        }
    }
    __syncthreads();
    if (tid < 64) {
        int b = tid >> 2, u = tid & 3;
        float G0 = 0.f, G1 = 0.f, G2 = 0.f, G3 = 0.f;
        const float* pp = s_part + b * 64 + u * 4;
#pragma unroll
        for (int k = 0; k < 4; k++) {
            G0 += pp[0 * 16 + k]; G1 += pp[1 * 16 + k];
            G2 += pp[2 * 16 + k]; G3 += pp[3 * 16 + k];
        }
        int j = blk * 4 + u;
        G0 += A.drnn_bih[j] + A.drnn_bhh[j];
        G1 += A.drnn_bih[1024 + j] + A.drnn_bhh[1024 + j];
        G2 += A.drnn_bih[2048 + j] + A.drnn_bhh[2048 + j];
        G3 += A.drnn_bih[3072 + j] + A.drnn_bhh[3072 + j];
        float ig = sigmf(G0), fg = sigmf(G1), gg = tanhfast(G2), og = sigmf(G3);
        float c = fg * ws[OFF_DECC + b * 1024 + j] + ig * gg;
        ws[OFF_DECC + b * 1024 + j] = c;
        ws[OFF_DECH + wp * 16384 + b * 1024 + j] = og * tanhfast(c);
    }
}

__global__ void __launch_bounds__(1024)
__attribute__((amdgpu_waves_per_eu(4, 4)))
decoder_main(DecArgs A) {
    const int tid = threadIdx.x;
    const int wv = tid >> 6;
    const int lane = tid & 63;
    const int blk = blockIdx.x;
    float* ws = A.ws;
    unsigned* bar = (unsigned*)(ws + OFF_BAR);

    // LDS
    __shared__ alignas(16) float s_in[10240];   // 40KB input staging (4 batches)
    __shared__ float s_part[1024];              // [16b][4gate][4unit][4kg]
    __shared__ float s_ah[1024];
    __shared__ float s_loc[128 * 33];
    __shared__ float s_pq[128];
    __shared__ float s_ev[128];
    __shared__ float s_aw2[128];
    __shared__ float s_awl[128];
    __shared__ float s_awcl[128];
    __shared__ float s_ep[1024];
    __shared__ float s_red[2];

    // thread layout for LSTM phases: wave = kg*4+gate ; lane = k16*4+r
    const int kg = wv >> 2;
    const int gate = wv & 3;
    const int k16 = lane >> 2;
    const int r = lane & 3;
    const int sid4 = (kg * 16 + k16) * 4;
    const int jrow = blk * 4 + r;
    const int arow = gate * 1024 + jrow;

    // ---- register-resident weights: named float4s, loaded once ----
    float4 wa0, wa1, wa2, wa3, wa4, wa5;         // attn: [ctx(512) | ah(1024)]
    {
        const float* wih = A.arnn_wih + (size_t)arow * 768 + 256;
        const float* whh = A.arnn_whh + (size_t)arow * 1024;
        wa0 = *(const float4*)(wih + 0 * 256 + sid4);
        wa1 = *(const float4*)(wih + 1 * 256 + sid4);
        wa2 = *(const float4*)(whh + 0 * 256 + sid4);
        wa3 = *(const float4*)(whh + 1 * 256 + sid4);
        wa4 = *(const float4*)(whh + 2 * 256 + sid4);
        wa5 = *(const float4*)(whh + 3 * 256 + sid4);
    }
    float4 wd0, wd1, wd2, wd3, wd4, wd5, wd6, wd7, wd8, wd9;  // dec: [ah|ctx|dh]
    {
        const float* wih = A.drnn_wih + (size_t)arow * 1536;
        const float* whh = A.drnn_whh + (size_t)arow * 1024;
        wd0 = *(const float4*)(wih + 0 * 256 + sid4);
        wd1 = *(const float4*)(wih + 1 * 256 + sid4);
        wd2 = *(const float4*)(wih + 2 * 256 + sid4);
        wd3 = *(const float4*)(wih + 3 * 256 + sid4);
        wd4 = *(const float4*)(wih + 4 * 256 + sid4);
        wd5 = *(const float4*)(wih + 5 * 256 + sid4);
        wd6 = *(const float4*)(whh + 0 * 256 + sid4);
        wd7 = *(const float4*)(whh + 1 * 256 + sid4);
        wd8 = *(const float4*)(whh + 2 * 256 + sid4);
        wd9 = *(const float4*)(whh + 3 * 256 + sid4);
    }

    auto attention = [&](int t, int wpar, int rpar) {
        const int b = blk;
        s_ah[tid] = ws[OFF_ATTNH + wpar * 16384 + b * 1024 + tid];
        if (tid < 128) {
            s_awl[tid] = ws[OFF_AW + rpar * 2048 + b * 128 + tid];
            s_awcl[tid] = ws[OFF_AWC + rpar * 2048 + b * 128 + tid];
        }
        __syncthreads();
        for (int idx = tid; idx < 4096; idx += 1024) {
            int f = idx >> 7, tt = idx & 127;
            const float* w0 = A.conv_w + f * 62;
            float s = 0.f;
#pragma unroll
            for (int k = 0; k < 31; k++) {
                int j = tt + k - 15;
                if (j >= 0 && j < 128) s += w0[k] * s_awl[j] + w0[31 + k] * s_awcl[j];
            }
            s_loc[tt * 33 + f] = s;
        }
        {
#pragma unroll
            for (int ii = 0; ii < 8; ii++) {
                int a = wv * 8 + ii;
                const float* qw = A.query_w + a * 1024;
                float s = 0.f;
#pragma unroll
                for (int q = 0; q < 4; q++) {
                    int k = q * 256 + lane * 4;
                    float4 h4 = *reinterpret_cast<const float4*>(&s_ah[k]);
                    float4 w4 = *reinterpret_cast<const float4*>(&qw[k]);
                    s += dot4(h4, w4);
                }
#pragma unroll
                for (int off = 1; off < 64; off <<= 1) s += __shfl_xor(s, off);
                if (lane == 0) s_pq[a] = s;
            }
        }
        __syncthreads();
        {
            int tt = tid >> 3, sl = tid & 7;
            float part = 0.f;
            for (int i = 0; i < 16; i++) {
                int a = i * 8 + sl;
                float lp = 0.f;
                const float* dw = A.dense_w + a * 32;
#pragma unroll
                for (int f = 0; f < 32; f++) lp += s_loc[tt * 33 + f] * dw[f];
                float arg = s_pq[a] + lp + ws[OFF_PM + (b * 128 + tt) * 128 + a];
                part += A.v_w[a] * tanhfast(arg);
            }
            s_ep[tid] = part;
        }
        __syncthreads();
        int ml = A.memlen[b];
        if (tid < 128) {
            float s = 0.f;
#pragma unroll
            for (int q = 0; q < 8; q++) s += s_ep[tid * 8 + q];
            if (tid >= ml) s = -1e30f;
            s_ev[tid] = s;
        }
        __syncthreads();
        if (wv == 0) {
            float m = fmaxf(s_ev[lane], s_ev[lane + 64]);
#pragma unroll
            for (int off = 1; off < 64; off <<= 1) m = fmaxf(m, __shfl_xor(m, off));
            if (lane == 0) s_red[0] = m;
        }
        __syncthreads();
        if (tid < 128) s_aw2[tid] = __expf(s_ev[tid] - s_red[0]);
        __syncthreads();
        if (wv == 0) {
            float s = s_aw2[lane] + s_aw2[lane + 64];
#pragma unroll
            for (int off = 1; off < 64; off <<= 1) s += __shfl_xor(s, off);
            if (lane == 0) s_red[1] = 1.f / s;
        }
        __syncthreads();
        if (tid < 128) {
            float val = s_aw2[tid] * s_red[1];
            s_aw2[tid] = val;
            ws[OFF_AW + wpar * 2048 + b * 128 + tid] = val;
            ws[OFF_AWC + wpar * 2048 + b * 128 + tid] = s_awcl[tid] + val;
            A.out[165888 + b * 16384 + t * 128 + tid] = val;  // alignments
        }
        __syncthreads();
        if (tid < 512) {
            const float* mb = A.memory + (size_t)b * 65536 + tid;
            float acc = 0.f;
            for (int tt2 = 0; tt2 < 128; tt2++) acc += s_aw2[tt2] * mb[tt2 * 512];
            ws[OFF_CTX + wpar * 8192 + b * 512 + tid] = acc;
        }
    };

    auto eout = [&](int tdone) {
        int widx = (blk - 16) * 16 + wv;
        if (widx >= 1296) return;
        int ppar = tdone & 1;
        int b; const float* wrow; float bias; float* dst;
        if (widx < 1280) {
            b = widx / 80; int m = widx % 80;
            wrow = A.proj_w + m * 1536; bias = A.proj_b[m];
            dst = A.out + (size_t)(b * 80 + m) * 128 + tdone;
        } else {
            b = widx - 1280;
            wrow = A.gate_w; bias = A.gate_b[0];
            dst = A.out + 163840 + b * 128 + tdone;
        }
        const float* h1p = ws + OFF_DECH + ppar * 16384 + b * 1024;
        const float* c1p = ws + OFF_CTX + ppar * 8192 + b * 512;
        float s = 0.f;
#pragma unroll
        for (int q = 0; q < 6; q++) {
            int k = q * 256 + lane * 4;
            float4 w4 = *reinterpret_cast<const float4*>(&wrow[k]);
            float4 h4;
            if (k < 1024) h4 = *reinterpret_cast<const float4*>(&h1p[k]);
            else h4 = *reinterpret_cast<const float4*>(&c1p[k - 1024]);
            s += dot4(w4, h4);
        }
#pragma unroll
        for (int off = 1; off < 64; off <<= 1) s += __shfl_xor(s, off);
        if (lane == 0) *dst = s + bias;
    };

    unsigned bt = 0;

    // P1(0): attn LSTM for t=0 (reads zeroed state)
    attn_lstm_phase(A, ws, s_in, s_part, tid, kg, gate, k16, r, blk, 0, 0, 1,
                    wa0, wa1, wa2, wa3, wa4, wa5);
    bt += 256; gridbar(bar, bt);

    for (int t = 0; t < 128; t++) {
        int wpar = t & 1, rpar = wpar ^ 1;
        if (blk < 16) attention(t, wpar, rpar);
        else if (t >= 1) eout(t - 1);
        bt += 256; gridbar(bar, bt);
        // dec LSTM(t), then attn LSTM(t+1) — independent of dec(t), no barrier
        dec_lstm_phase(A, ws, s_in, s_part, tid, kg, gate, k16, r, blk, wpar, rpar,
                       wd0, wd1, wd2, wd3, wd4, wd5, wd6, wd7, wd8, wd9);
        if (t + 1 < 128) {
            attn_lstm_phase(A, ws, s_in, s_part, tid, kg, gate, k16, r, blk,
                            t + 1, rpar, wpar, wa0, wa1, wa2, wa3, wa4, wa5);
        }
        bt += 256; gridbar(bar, bt);
    }
    if (blk >= 16) eout(127);
}

// ---------------- launcher ----------------

extern "C" void kernel_launch(void* const* d_in, const int* in_sizes, int n_in,
                              void* d_out, int out_size, void* d_ws, size_t ws_size,
                              hipStream_t stream) {
    (void)in_sizes; (void)n_in; (void)out_size; (void)ws_size;
    const float* memory    = (const float*)d_in[0];
    const float* mels      = (const float*)d_in[1];
    const int*   memlen    = (const int*)d_in[2];
    const float* prenet_w1 = (const float*)d_in[3];
    const float* prenet_w2 = (const float*)d_in[4];
    const float* arnn_wih  = (const float*)d_in[5];
    const float* arnn_whh  = (const float*)d_in[6];
    const float* arnn_bih  = (const float*)d_in[7];
    const float* arnn_bhh  = (const float*)d_in[8];
    const float* query_w   = (const float*)d_in[9];
    const float* memory_w  = (const float*)d_in[10];
    const float* v_w       = (const float*)d_in[11];
    const float* conv_w    = (const float*)d_in[12];
    const float* dense_w   = (const float*)d_in[13];
    const float* drnn_wih  = (const float*)d_in[14];
    const float* drnn_whh  = (const float*)d_in[15];
    const float* drnn_bih  = (const float*)d_in[16];
    const float* drnn_bhh  = (const float*)d_in[17];
    const float* proj_w    = (const float*)d_in[18];
    const float* proj_b    = (const float*)d_in[19];
    const float* gate_w    = (const float*)d_in[20];
    const float* gate_b    = (const float*)d_in[21];
    float* ws = (float*)d_ws;
    float* out = (float*)d_out;

    // zero recurrent state + barrier counter (ws is poisoned 0xAA each call)
    hipMemsetAsync(ws + OFF_ATTNH, 0, (STATE_FLOATS + 16) * sizeof(float), stream);

    build_decin<<<dim3(160), dim3(1024), 0, stream>>>(mels, ws + OFF_DECIN);
    gemm_kernel<<<dim3(4, 32), dim3(256), 0, stream>>>(ws + OFF_DECIN, 80, prenet_w1, 80,
                                                       ws + OFF_H1, 256, 2048, 256, 80,
                                                       nullptr, nullptr, 1);
    gemm_kernel<<<dim3(4, 32), dim3(256), 0, stream>>>(ws + OFF_H1, 256, prenet_w2, 256,
                                                       ws + OFF_X, 256, 2048, 256, 256,
                                                       nullptr, nullptr, 1);
    gemm_kernel<<<dim3(64, 32), dim3(256), 0, stream>>>(ws + OFF_X, 256, arnn_wih, 768,
                                                        ws + OFF_XA, 4096, 2048, 4096, 256,
                                                        arnn_bih, arnn_bhh, 0);
    gemm_kernel<<<dim3(2, 32), dim3(256), 0, stream>>>(memory, 512, memory_w, 512,
                                                       ws + OFF_PM, 128, 2048, 128, 512,
                                                       nullptr, nullptr, 0);

    DecArgs a;
    a.memory = memory; a.memlen = memlen;
    a.arnn_wih = arnn_wih; a.arnn_whh = arnn_whh;
    a.drnn_wih = drnn_wih; a.drnn_whh = drnn_whh;
    a.drnn_bih = drnn_bih; a.drnn_bhh = drnn_bhh;
    a.query_w = query_w; a.v_w = v_w;
    a.conv_w = conv_w; a.dense_w = dense_w;
    a.proj_w = proj_w; a.proj_b = proj_b;
    a.gate_w = gate_w; a.gate_b = gate_b;
    a.ws = ws; a.out = out;
    void* kargs[] = { &a };
    hipLaunchCooperativeKernel((const void*)decoder_main, dim3(256), dim3(1024),
                               kargs, 0, stream);
}

// Round 5
// 43434.332 us; speedup vs baseline: 1.7600x; 1.2494x over previous
//
#include <hip/hip_runtime.h>

// Problem constants
#define N_MEL 80
#define ENC   512
#define ARNN  1024
#define PRE   256
#define ADIM  128
#define NFILT 32
#define KS    31
#define BSZ   16
#define TENC  128
#define TDEC  128

// Workspace layout (float offsets)
#define OFF_XA     0u          // [128][16][4096] precomputed x@Wih_x^T + bih + bhh
#define OFF_X      8388608u    // [128][16][256]  prenet out
#define OFF_H1     8912896u    // [128][16][256]  prenet hidden
#define OFF_DECIN  9437184u    // [128][16][80]
#define OFF_PM     9601024u    // [16][128][128]  processed memory
#define OFF_ATTNH  9863168u    // [2][16][1024]
#define OFF_ATTNC  9895936u    // [16][1024]
#define OFF_DECH   9912320u    // [2][16][1024]
#define OFF_DECC   9945088u    // [16][1024]
#define OFF_CTX    9961472u    // [2][16][512]
#define OFF_AW     9977856u    // [2][16][128]
#define OFF_AWC    9981952u    // [2][16][128]
#define STATE_FLOATS 122880    // from OFF_ATTNH to end of AWC
#define OFF_BAR    (OFF_ATTNH + STATE_FLOATS)   // barrier counter (1 word, zeroed)

__device__ __forceinline__ float sigmf(float x) { return 1.0f / (1.0f + __expf(-x)); }
__device__ __forceinline__ float tanhfast(float x) { return 1.0f - 2.0f / (__expf(2.0f * x) + 1.0f); }
__device__ __forceinline__ float dot4(float4 a, float4 b) {
    return a.x * b.x + a.y * b.y + a.z * b.z + a.w * b.w;
}

// ---------------- precompute kernels ----------------

__global__ void __launch_bounds__(1024) build_decin(const float* __restrict__ mels,
                                                    float* __restrict__ decin) {
    int idx = blockIdx.x * 1024 + threadIdx.x;  // 128*16*80 = 163840
    if (idx >= 128 * 16 * 80) return;
    int t = idx / 1280, r = idx % 1280;
    int b = r / 80, m = r % 80;
    decin[idx] = (t == 0) ? 0.f : mels[b * (80 * 128) + m * 128 + (t - 1)];
}

// C[M][N] = act(A[M][K] @ B[N][K]^T + bias1 + bias2); M,N multiples of 64.
__global__ void __launch_bounds__(256) gemm_kernel(
    const float* __restrict__ A, int lda,
    const float* __restrict__ B, int ldb,
    float* __restrict__ C, int ldc,
    int M, int N, int K,
    const float* __restrict__ bias1, const float* __restrict__ bias2, int relu) {
    __shared__ float As[16][68];
    __shared__ float Bs[16][68];
    int tid = threadIdx.x;
    int tn = tid & 15, tm = tid >> 4;
    int m0 = blockIdx.y * 64, n0 = blockIdx.x * 64;
    float acc[4][4] = {};
    for (int k0 = 0; k0 < K; k0 += 16) {
        for (int idx = tid; idx < 1024; idx += 256) {
            int mm = idx >> 4, kk = idx & 15;
            int kg = k0 + kk;
            As[kk][mm] = (kg < K) ? A[(size_t)(m0 + mm) * lda + kg] : 0.f;
            Bs[kk][mm] = (kg < K) ? B[(size_t)(n0 + mm) * ldb + kg] : 0.f;
        }
        __syncthreads();
#pragma unroll
        for (int kk = 0; kk < 16; kk++) {
            float av[4], bv[4];
#pragma unroll
            for (int i = 0; i < 4; i++) { av[i] = As[kk][tm * 4 + i]; bv[i] = Bs[kk][tn * 4 + i]; }
#pragma unroll
            for (int i = 0; i < 4; i++)
#pragma unroll
                for (int j = 0; j < 4; j++) acc[i][j] += av[i] * bv[j];
        }
        __syncthreads();
    }
    for (int i = 0; i < 4; i++) {
        int m = m0 + tm * 4 + i;
        for (int j = 0; j < 4; j++) {
            int n = n0 + tn * 4 + j;
            float v = acc[i][j];
            if (bias1) v += bias1[n];
            if (bias2) v += bias2[n];
            if (relu) v = fmaxf(v, 0.f);
            C[(size_t)m * ldc + n] = v;
        }
    }
}

// ---------------- main persistent cooperative kernel ----------------

struct DecArgs {
    const float* memory;
    const int* memlen;
    const float* arnn_wih;
    const float* arnn_whh;
    const float* drnn_wih;
    const float* drnn_whh;
    const float* drnn_bih;
    const float* drnn_bhh;
    const float* query_w;
    const float* v_w;
    const float* conv_w;
    const float* dense_w;
    const float* proj_w;
    const float* proj_b;
    const float* gate_w;
    const float* gate_b;
    float* ws;
    float* out;
};

// Lightweight grid barrier: monotonic counter in device memory.
__device__ __forceinline__ void gridbar(unsigned* bar, unsigned target) {
    __syncthreads();
    __threadfence();   // release
    if (threadIdx.x == 0) {
        atomicAdd(bar, 1u);
        while (__hip_atomic_load(bar, __ATOMIC_RELAXED, __HIP_MEMORY_SCOPE_AGENT) < target) {
            __builtin_amdgcn_s_sleep(2);
        }
    }
    __syncthreads();
    __threadfence();   // acquire
}

// Attention LSTM for step t: weights passed BY VALUE (registers).
__device__ __forceinline__ void attn_lstm_phase(
    const DecArgs& A, float* ws, float* s_in, float* s_part,
    int tid, int kg, int gate, int k16, int r, int blk, int t, int wp, int rp,
    float4 wa0, float4 wa1, float4 wa2, float4 wa3, float4 wa4, float4 wa5) {
    const int sid4 = (kg * 16 + k16) * 4;
    // prefetch XA (x-part of gates) for the finalize threads — issues early,
    // consumed after the reduction.
    float xa0 = 0.f, xa1 = 0.f, xa2 = 0.f, xa3 = 0.f;
    if (tid < 64) {
        int b = tid >> 2, u = tid & 3;
        const float* xa = ws + OFF_XA + (size_t)(t * 16 + b) * 4096;
        int j = blk * 4 + u;
        xa0 = xa[j]; xa1 = xa[1024 + j]; xa2 = xa[2048 + j]; xa3 = xa[3072 + j];
    }
    for (int g4 = 0; g4 < 4; ++g4) {
        __syncthreads();
#pragma unroll
        for (int bb4 = 0; bb4 < 4; ++bb4) {
            int b = g4 * 4 + bb4;
            const float* ctx = ws + OFF_CTX + rp * 8192 + b * 512;
            const float* ah  = ws + OFF_ATTNH + rp * 16384 + b * 1024;
            float* dst = s_in + bb4 * 1536;
            dst[tid] = (tid < 512) ? ctx[tid] : ah[tid - 512];
            if (tid < 512) dst[1024 + tid] = ah[512 + tid];
        }
        __syncthreads();
#pragma unroll
        for (int bb4 = 0; bb4 < 4; ++bb4) {
            const float* xp = s_in + bb4 * 1536 + sid4;
            float4 x0 = *(const float4*)(xp);
            float4 x1 = *(const float4*)(xp + 256);
            float4 x2 = *(const float4*)(xp + 512);
            float4 x3 = *(const float4*)(xp + 768);
            float4 x4 = *(const float4*)(xp + 1024);
            float4 x5 = *(const float4*)(xp + 1280);
            float a = dot4(wa0, x0) + dot4(wa1, x1) + dot4(wa2, x2)
                    + dot4(wa3, x3) + dot4(wa4, x4) + dot4(wa5, x5);
            a += __shfl_xor(a, 4);
            a += __shfl_xor(a, 8);
            a += __shfl_xor(a, 16);
            a += __shfl_xor(a, 32);
            if (k16 == 0) s_part[((g4 * 4 + bb4) * 16 + gate * 4 + r) * 4 + kg] = a;
        }
    }
    __syncthreads();
    if (tid < 64) {
        int b = tid >> 2, u = tid & 3;
        float G0 = xa0, G1 = xa1, G2 = xa2, G3 = xa3;
        const float* pp = s_part + b * 64 + u * 4;
#pragma unroll
        for (int k = 0; k < 4; k++) {
            G0 += pp[0 * 16 + k]; G1 += pp[1 * 16 + k];
            G2 += pp[2 * 16 + k]; G3 += pp[3 * 16 + k];
        }
        int j = blk * 4 + u;
        float ig = sigmf(G0), fg = sigmf(G1), gg = tanhfast(G2), og = sigmf(G3);
        float c = fg * ws[OFF_ATTNC + b * 1024 + j] + ig * gg;
        ws[OFF_ATTNC + b * 1024 + j] = c;
        ws[OFF_ATTNH + wp * 16384 + b * 1024 + j] = og * tanhfast(c);
    }
}

// Decoder LSTM for step t. Bias sums (step-invariant) passed in registers.
__device__ __forceinline__ void dec_lstm_phase(
    const DecArgs& A, float* ws, float* s_in, float* s_part,
    int tid, int kg, int gate, int k16, int r, int blk, int wp, int rp,
    float bs0, float bs1, float bs2, float bs3,
    float4 wd0, float4 wd1, float4 wd2, float4 wd3, float4 wd4,
    float4 wd5, float4 wd6, float4 wd7, float4 wd8, float4 wd9) {
    const int sid4 = (kg * 16 + k16) * 4;
    for (int g4 = 0; g4 < 4; ++g4) {
        __syncthreads();
#pragma unroll
        for (int bb4 = 0; bb4 < 4; ++bb4) {
            int b = g4 * 4 + bb4;
            const float* ah  = ws + OFF_ATTNH + wp * 16384 + b * 1024;
            const float* ctx = ws + OFF_CTX + wp * 8192 + b * 512;
            const float* dh  = ws + OFF_DECH + rp * 16384 + b * 1024;
            float* dst = s_in + bb4 * 2560;
            dst[tid] = ah[tid];
            dst[1024 + tid] = (tid < 512) ? ctx[tid] : dh[tid - 512];
            if (tid < 512) dst[2048 + tid] = dh[512 + tid];
        }
        __syncthreads();
#pragma unroll
        for (int bb4 = 0; bb4 < 4; ++bb4) {
            const float* xp = s_in + bb4 * 2560 + sid4;
            float a;
            {
                float4 x0 = *(const float4*)(xp);
                float4 x1 = *(const float4*)(xp + 256);
                float4 x2 = *(const float4*)(xp + 512);
                float4 x3 = *(const float4*)(xp + 768);
                float4 x4 = *(const float4*)(xp + 1024);
                a = dot4(wd0, x0) + dot4(wd1, x1) + dot4(wd2, x2)
                  + dot4(wd3, x3) + dot4(wd4, x4);
            }
            {
                float4 x5 = *(const float4*)(xp + 1280);
                float4 x6 = *(const float4*)(xp + 1536);
                float4 x7 = *(const float4*)(xp + 1792);
                float4 x8 = *(const float4*)(xp + 2048);
                float4 x9 = *(const float4*)(xp + 2304);
                a += dot4(wd5, x5) + dot4(wd6, x6) + dot4(wd7, x7)
                   + dot4(wd8, x8) + dot4(wd9, x9);
            }
            a += __shfl_xor(a, 4);
            a += __shfl_xor(a, 8);
            a += __shfl_xor(a, 16);
            a += __shfl_xor(a, 32);
            if (k16 == 0) s_part[((g4 * 4 + bb4) * 16 + gate * 4 + r) * 4 + kg] = a;
        }
    }
    __syncthreads();
    if (tid < 64) {
        int b = tid >> 2, u = tid & 3;
        float G0 = bs0, G1 = bs1, G2 = bs2, G3 = bs3;
        const float* pp = s_part + b * 64 + u * 4;
#pragma unroll
        for (int k = 0; k < 4; k++) {
            G0 += pp[0 * 16 + k]; G1 += pp[1 * 16 + k];
            G2 += pp[2 * 16 + k]; G3 += pp[3 * 16 + k];
        }
        int j = blk * 4 + u;
        float ig = sigmf(G0), fg = sigmf(G1), gg = tanhfast(G2), og = sigmf(G3);
        float c = fg * ws[OFF_DECC + b * 1024 + j] + ig * gg;
        ws[OFF_DECC + b * 1024 + j] = c;
        ws[OFF_DECH + wp * 16384 + b * 1024 + j] = og * tanhfast(c);
    }
}

// __launch_bounds__(1024, 4): 16-wave block, 4 waves/EU min -> VGPR cap 128,
// 1 block/CU. This is what lets the 64 weight VGPRs stay resident.
__global__ void __launch_bounds__(1024, 4) decoder_main(DecArgs A) {
    const int tid = threadIdx.x;
    const int wv = tid >> 6;
    const int lane = tid & 63;
    const int blk = blockIdx.x;
    float* ws = A.ws;
    unsigned* bar = (unsigned*)(ws + OFF_BAR);

    // LDS
    __shared__ alignas(16) float s_in[10240];   // 40KB input staging (4 batches)
    __shared__ float s_part[1024];              // [16b][4gate][4unit][4kg]
    __shared__ float s_ah[1024];
    __shared__ float s_loc[128 * 33];
    __shared__ float s_cw[62 * 32];             // conv weights, [k][f]
    __shared__ float s_dw[128 * 33];            // dense weights, [a][f] padded
    __shared__ float s_pq[128];
    __shared__ float s_ev[128];
    __shared__ float s_aw2[128];
    __shared__ float s_awl[128];
    __shared__ float s_awcl[128];
    __shared__ float s_ep[1024];
    __shared__ float s_red[2];

    // thread layout for LSTM phases: wave = kg*4+gate ; lane = k16*4+r
    const int kg = wv >> 2;
    const int gate = wv & 3;
    const int k16 = lane >> 2;
    const int r = lane & 3;
    const int sid4 = (kg * 16 + k16) * 4;
    const int jrow = blk * 4 + r;
    const int arow = gate * 1024 + jrow;

    // ---- register-resident weights: named float4s, loaded once ----
    float4 wa0, wa1, wa2, wa3, wa4, wa5;         // attn: [ctx(512) | ah(1024)]
    {
        const float* wih = A.arnn_wih + (size_t)arow * 768 + 256;
        const float* whh = A.arnn_whh + (size_t)arow * 1024;
        wa0 = *(const float4*)(wih + 0 * 256 + sid4);
        wa1 = *(const float4*)(wih + 1 * 256 + sid4);
        wa2 = *(const float4*)(whh + 0 * 256 + sid4);
        wa3 = *(const float4*)(whh + 1 * 256 + sid4);
        wa4 = *(const float4*)(whh + 2 * 256 + sid4);
        wa5 = *(const float4*)(whh + 3 * 256 + sid4);
    }
    float4 wd0, wd1, wd2, wd3, wd4, wd5, wd6, wd7, wd8, wd9;  // dec: [ah|ctx|dh]
    {
        const float* wih = A.drnn_wih + (size_t)arow * 1536;
        const float* whh = A.drnn_whh + (size_t)arow * 1024;
        wd0 = *(const float4*)(wih + 0 * 256 + sid4);
        wd1 = *(const float4*)(wih + 1 * 256 + sid4);
        wd2 = *(const float4*)(wih + 2 * 256 + sid4);
        wd3 = *(const float4*)(wih + 3 * 256 + sid4);
        wd4 = *(const float4*)(wih + 4 * 256 + sid4);
        wd5 = *(const float4*)(wih + 5 * 256 + sid4);
        wd6 = *(const float4*)(whh + 0 * 256 + sid4);
        wd7 = *(const float4*)(whh + 1 * 256 + sid4);
        wd8 = *(const float4*)(whh + 2 * 256 + sid4);
        wd9 = *(const float4*)(whh + 3 * 256 + sid4);
    }
    // step-invariant decoder bias sums (finalize threads only)
    float bs0 = 0.f, bs1 = 0.f, bs2 = 0.f, bs3 = 0.f;
    if (tid < 64) {
        int j = blk * 4 + (tid & 3);
        bs0 = A.drnn_bih[j] + A.drnn_bhh[j];
        bs1 = A.drnn_bih[1024 + j] + A.drnn_bhh[1024 + j];
        bs2 = A.drnn_bih[2048 + j] + A.drnn_bhh[2048 + j];
        bs3 = A.drnn_bih[3072 + j] + A.drnn_bhh[3072 + j];
    }
    // stage small attention weights in LDS (attention blocks only)
    if (blk < 16) {
        for (int i = tid; i < 62 * 32; i += 1024) {
            int k = i >> 5, f = i & 31;
            s_cw[k * 32 + f] = A.conv_w[f * 62 + k];
        }
        for (int i = tid; i < 128 * 32; i += 1024) {
            int a = i >> 5, f = i & 31;
            s_dw[a * 33 + f] = A.dense_w[a * 32 + f];
        }
    }

    auto attention = [&](int t, int wpar, int rpar) {
        const int b = blk;
        s_ah[tid] = ws[OFF_ATTNH + wpar * 16384 + b * 1024 + tid];
        if (tid < 128) {
            s_awl[tid] = ws[OFF_AW + rpar * 2048 + b * 128 + tid];
            s_awcl[tid] = ws[OFF_AWC + rpar * 2048 + b * 128 + tid];
        }
        __syncthreads();
        // location conv from LDS weights (low register pressure)
        for (int idx = tid; idx < 4096; idx += 1024) {
            int f = idx >> 7, tt = idx & 127;
            float s = 0.f;
#pragma unroll 1
            for (int k = 0; k < 31; k++) {
                int j = tt + k - 15;
                float c0 = s_cw[k * 32 + f];
                float c1 = s_cw[(31 + k) * 32 + f];
                if (j >= 0 && j < 128) s += c0 * s_awl[j] + c1 * s_awcl[j];
            }
            s_loc[tt * 33 + f] = s;
        }
        {
#pragma unroll 1
            for (int ii = 0; ii < 8; ii++) {
                int a = wv * 8 + ii;
                const float* qw = A.query_w + a * 1024;
                float s = 0.f;
#pragma unroll
                for (int q = 0; q < 4; q++) {
                    int k = q * 256 + lane * 4;
                    float4 h4 = *reinterpret_cast<const float4*>(&s_ah[k]);
                    float4 w4 = *reinterpret_cast<const float4*>(&qw[k]);
                    s += dot4(h4, w4);
                }
#pragma unroll
                for (int off = 1; off < 64; off <<= 1) s += __shfl_xor(s, off);
                if (lane == 0) s_pq[a] = s;
            }
        }
        __syncthreads();
        {
            int tt = tid >> 3, sl = tid & 7;
            float part = 0.f;
#pragma unroll 1
            for (int i = 0; i < 16; i++) {
                int a = i * 8 + sl;
                float lp = 0.f;
                for (int f = 0; f < 32; f++) lp += s_loc[tt * 33 + f] * s_dw[a * 33 + f];
                float arg = s_pq[a] + lp + ws[OFF_PM + (b * 128 + tt) * 128 + a];
                part += A.v_w[a] * tanhfast(arg);
            }
            s_ep[tid] = part;
        }
        __syncthreads();
        int ml = A.memlen[b];
        if (tid < 128) {
            float s = 0.f;
#pragma unroll
            for (int q = 0; q < 8; q++) s += s_ep[tid * 8 + q];
            if (tid >= ml) s = -1e30f;
            s_ev[tid] = s;
        }
        __syncthreads();
        if (wv == 0) {
            float m = fmaxf(s_ev[lane], s_ev[lane + 64]);
#pragma unroll
            for (int off = 1; off < 64; off <<= 1) m = fmaxf(m, __shfl_xor(m, off));
            if (lane == 0) s_red[0] = m;
        }
        __syncthreads();
        if (tid < 128) s_aw2[tid] = __expf(s_ev[tid] - s_red[0]);
        __syncthreads();
        if (wv == 0) {
            float s = s_aw2[lane] + s_aw2[lane + 64];
#pragma unroll
            for (int off = 1; off < 64; off <<= 1) s += __shfl_xor(s, off);
            if (lane == 0) s_red[1] = 1.f / s;
        }
        __syncthreads();
        if (tid < 128) {
            float val = s_aw2[tid] * s_red[1];
            s_aw2[tid] = val;
            ws[OFF_AW + wpar * 2048 + b * 128 + tid] = val;
            ws[OFF_AWC + wpar * 2048 + b * 128 + tid] = s_awcl[tid] + val;
            A.out[165888 + b * 16384 + t * 128 + tid] = val;  // alignments
        }
        __syncthreads();
        if (tid < 512) {
            const float* mb = A.memory + (size_t)b * 65536 + tid;
            float acc = 0.f;
#pragma unroll 8
            for (int tt2 = 0; tt2 < 128; tt2++) acc += s_aw2[tt2] * mb[tt2 * 512];
            ws[OFF_CTX + wpar * 8192 + b * 512 + tid] = acc;
        }
    };

    auto eout = [&](int tdone) {
        int widx = (blk - 16) * 16 + wv;
        if (widx >= 1296) return;
        int ppar = tdone & 1;
        int b; const float* wrow; float bias; float* dst;
        if (widx < 1280) {
            b = widx / 80; int m = widx % 80;
            wrow = A.proj_w + m * 1536; bias = A.proj_b[m];
            dst = A.out + (size_t)(b * 80 + m) * 128 + tdone;
        } else {
            b = widx - 1280;
            wrow = A.gate_w; bias = A.gate_b[0];
            dst = A.out + 163840 + b * 128 + tdone;
        }
        const float* h1p = ws + OFF_DECH + ppar * 16384 + b * 1024;
        const float* c1p = ws + OFF_CTX + ppar * 8192 + b * 512;
        float s = 0.f;
#pragma unroll 1
        for (int q = 0; q < 6; q++) {
            int k = q * 256 + lane * 4;
            float4 w4 = *reinterpret_cast<const float4*>(&wrow[k]);
            float4 h4;
            if (k < 1024) h4 = *reinterpret_cast<const float4*>(&h1p[k]);
            else h4 = *reinterpret_cast<const float4*>(&c1p[k - 1024]);
            s += dot4(w4, h4);
        }
#pragma unroll
        for (int off = 1; off < 64; off <<= 1) s += __shfl_xor(s, off);
        if (lane == 0) *dst = s + bias;
    };

    unsigned bt = 0;

    // P1(0): attn LSTM for t=0 (reads zeroed state)
    attn_lstm_phase(A, ws, s_in, s_part, tid, kg, gate, k16, r, blk, 0, 0, 1,
                    wa0, wa1, wa2, wa3, wa4, wa5);
    bt += 256; gridbar(bar, bt);

    for (int t = 0; t < 128; t++) {
        int wpar = t & 1, rpar = wpar ^ 1;
        if (blk < 16) attention(t, wpar, rpar);
        else if (t >= 1) eout(t - 1);
        bt += 256; gridbar(bar, bt);
        // dec LSTM(t), then attn LSTM(t+1) — independent of dec(t), no barrier
        dec_lstm_phase(A, ws, s_in, s_part, tid, kg, gate, k16, r, blk, wpar, rpar,
                       bs0, bs1, bs2, bs3,
                       wd0, wd1, wd2, wd3, wd4, wd5, wd6, wd7, wd8, wd9);
        if (t + 1 < 128) {
            attn_lstm_phase(A, ws, s_in, s_part, tid, kg, gate, k16, r, blk,
                            t + 1, rpar, wpar, wa0, wa1, wa2, wa3, wa4, wa5);
        }
        bt += 256; gridbar(bar, bt);
    }
    if (blk >= 16) eout(127);
}

// ---------------- launcher ----------------

extern "C" void kernel_launch(void* const* d_in, const int* in_sizes, int n_in,
                              void* d_out, int out_size, void* d_ws, size_t ws_size,
                              hipStream_t stream) {
    (void)in_sizes; (void)n_in; (void)out_size; (void)ws_size;
    const float* memory    = (const float*)d_in[0];
    const float* mels      = (const float*)d_in[1];
    const int*   memlen    = (const int*)d_in[2];
    const float* prenet_w1 = (const float*)d_in[3];
    const float* prenet_w2 = (const float*)d_in[4];
    const float* arnn_wih  = (const float*)d_in[5];
    const float* arnn_whh  = (const float*)d_in[6];
    const float* arnn_bih  = (const float*)d_in[7];
    const float* arnn_bhh  = (const float*)d_in[8];
    const float* query_w   = (const float*)d_in[9];
    const float* memory_w  = (const float*)d_in[10];
    const float* v_w       = (const float*)d_in[11];
    const float* conv_w    = (const float*)d_in[12];
    const float* dense_w   = (const float*)d_in[13];
    const float* drnn_wih  = (const float*)d_in[14];
    const float* drnn_whh  = (const float*)d_in[15];
    const float* drnn_bih  = (const float*)d_in[16];
    const float* drnn_bhh  = (const float*)d_in[17];
    const float* proj_w    = (const float*)d_in[18];
    const float* proj_b    = (const float*)d_in[19];
    const float* gate_w    = (const float*)d_in[20];
    const float* gate_b    = (const float*)d_in[21];
    float* ws = (float*)d_ws;
    float* out = (float*)d_out;

    // zero recurrent state + barrier counter (ws is poisoned 0xAA each call)
    hipMemsetAsync(ws + OFF_ATTNH, 0, (STATE_FLOATS + 16) * sizeof(float), stream);

    build_decin<<<dim3(160), dim3(1024), 0, stream>>>(mels, ws + OFF_DECIN);
    gemm_kernel<<<dim3(4, 32), dim3(256), 0, stream>>>(ws + OFF_DECIN, 80, prenet_w1, 80,
                                                       ws + OFF_H1, 256, 2048, 256, 80,
                                                       nullptr, nullptr, 1);
    gemm_kernel<<<dim3(4, 32), dim3(256), 0, stream>>>(ws + OFF_H1, 256, prenet_w2, 256,
                                                       ws + OFF_X, 256, 2048, 256, 256,
                                                       nullptr, nullptr, 1);
    gemm_kernel<<<dim3(64, 32), dim3(256), 0, stream>>>(ws + OFF_X, 256, arnn_wih, 768,
                                                        ws + OFF_XA, 4096, 2048, 4096, 256,
                                                        arnn_bih, arnn_bhh, 0);
    gemm_kernel<<<dim3(2, 32), dim3(256), 0, stream>>>(memory, 512, memory_w, 512,
                                                       ws + OFF_PM, 128, 2048, 128, 512,
                                                       nullptr, nullptr, 0);

    DecArgs a;
    a.memory = memory; a.memlen = memlen;
    a.arnn_wih = arnn_wih; a.arnn_whh = arnn_whh;
    a.drnn_wih = drnn_wih; a.drnn_whh = drnn_whh;
    a.drnn_bih = drnn_bih; a.drnn_bhh = drnn_bhh;
    a.query_w = query_w; a.v_w = v_w;
    a.conv_w = conv_w; a.dense_w = dense_w;
    a.proj_w = proj_w; a.proj_b = proj_b;
    a.gate_w = gate_w; a.gate_b = gate_b;
    a.ws = ws; a.out = out;
    void* kargs[] = { &a };
    hipLaunchCooperativeKernel((const void*)decoder_main, dim3(256), dim3(1024),
                               kargs, 0, stream);
}

// Round 6
// 39652.609 us; speedup vs baseline: 1.9278x; 1.0954x over previous
//
#include <hip/hip_runtime.h>

// Problem constants
#define N_MEL 80
#define ENC   512
#define ARNN  1024
#define PRE   256
#define ADIM  128
#define NFILT 32
#define KS    31
#define BSZ   16
#define TENC  128
#define TDEC  128

// Workspace layout (float offsets)
#define OFF_XA     0u          // [128][16][4096] precomputed x@Wih_x^T + bih + bhh
#define OFF_X      8388608u    // [128][16][256]  prenet out
#define OFF_H1     8912896u    // [128][16][256]  prenet hidden
#define OFF_DECIN  9437184u    // [128][16][80]
#define OFF_PM     9601024u    // [16][128][128]  processed memory
#define OFF_ATTNH  9863168u    // [2][16][1024]
#define OFF_ATTNC  9895936u    // [16][1024]
#define OFF_DECH   9912320u    // [2][16][1024]
#define OFF_DECC   9945088u    // [16][1024]
#define OFF_CTX    9961472u    // [2][16][512]
#define OFF_AW     9977856u    // [2][16][128]
#define OFF_AWC    9981952u    // [2][16][128]
#define STATE_FLOATS 122880    // from OFF_ATTNH to end of AWC
#define OFF_BAR    (OFF_ATTNH + STATE_FLOATS)   // barrier counter (1 word, zeroed)

__device__ __forceinline__ float sigmf(float x) { return 1.0f / (1.0f + __expf(-x)); }
__device__ __forceinline__ float tanhfast(float x) { return 1.0f - 2.0f / (__expf(2.0f * x) + 1.0f); }
__device__ __forceinline__ float dot4(float4 a, float4 b) {
    return a.x * b.x + a.y * b.y + a.z * b.z + a.w * b.w;
}

// Pin a float4's components into VGPRs: the empty asm is an opaque def, so the
// register allocator cannot rematerialize the originating loads. This is what
// actually makes the weights register-resident (VGPR_Count=64 in r4/r5 proved
// plain by-value float4s get remat'd into per-step global reloads).
#define PIN4(v) asm volatile("" : "+v"((v).x), "+v"((v).y), "+v"((v).z), "+v"((v).w))

// ---------------- precompute kernels ----------------

__global__ void __launch_bounds__(1024) build_decin(const float* __restrict__ mels,
                                                    float* __restrict__ decin) {
    int idx = blockIdx.x * 1024 + threadIdx.x;  // 128*16*80 = 163840
    if (idx >= 128 * 16 * 80) return;
    int t = idx / 1280, r = idx % 1280;
    int b = r / 80, m = r % 80;
    decin[idx] = (t == 0) ? 0.f : mels[b * (80 * 128) + m * 128 + (t - 1)];
}

// C[M][N] = act(A[M][K] @ B[N][K]^T + bias1 + bias2); M,N multiples of 64.
__global__ void __launch_bounds__(256) gemm_kernel(
    const float* __restrict__ A, int lda,
    const float* __restrict__ B, int ldb,
    float* __restrict__ C, int ldc,
    int M, int N, int K,
    const float* __restrict__ bias1, const float* __restrict__ bias2, int relu) {
    __shared__ float As[16][68];
    __shared__ float Bs[16][68];
    int tid = threadIdx.x;
    int tn = tid & 15, tm = tid >> 4;
    int m0 = blockIdx.y * 64, n0 = blockIdx.x * 64;
    float acc[4][4] = {};
    for (int k0 = 0; k0 < K; k0 += 16) {
        for (int idx = tid; idx < 1024; idx += 256) {
            int mm = idx >> 4, kk = idx & 15;
            int kg = k0 + kk;
            As[kk][mm] = (kg < K) ? A[(size_t)(m0 + mm) * lda + kg] : 0.f;
            Bs[kk][mm] = (kg < K) ? B[(size_t)(n0 + mm) * ldb + kg] : 0.f;
        }
        __syncthreads();
#pragma unroll
        for (int kk = 0; kk < 16; kk++) {
            float av[4], bv[4];
#pragma unroll
            for (int i = 0; i < 4; i++) { av[i] = As[kk][tm * 4 + i]; bv[i] = Bs[kk][tn * 4 + i]; }
#pragma unroll
            for (int i = 0; i < 4; i++)
#pragma unroll
                for (int j = 0; j < 4; j++) acc[i][j] += av[i] * bv[j];
        }
        __syncthreads();
    }
    for (int i = 0; i < 4; i++) {
        int m = m0 + tm * 4 + i;
        for (int j = 0; j < 4; j++) {
            int n = n0 + tn * 4 + j;
            float v = acc[i][j];
            if (bias1) v += bias1[n];
            if (bias2) v += bias2[n];
            if (relu) v = fmaxf(v, 0.f);
            C[(size_t)m * ldc + n] = v;
        }
    }
}

// ---------------- main persistent cooperative kernel ----------------

struct DecArgs {
    const float* memory;
    const int* memlen;
    const float* arnn_wih;
    const float* arnn_whh;
    const float* drnn_wih;
    const float* drnn_whh;
    const float* drnn_bih;
    const float* drnn_bhh;
    const float* query_w;
    const float* v_w;
    const float* conv_w;
    const float* dense_w;
    const float* proj_w;
    const float* proj_b;
    const float* gate_w;
    const float* gate_b;
    float* ws;
    float* out;
};

// Lightweight grid barrier: monotonic counter in device memory.
__device__ __forceinline__ void gridbar(unsigned* bar, unsigned target) {
    __syncthreads();
    __threadfence();   // release (L2 writeback on gfx950 — dirty set is small)
    if (threadIdx.x == 0) {
        atomicAdd(bar, 1u);
        while (__hip_atomic_load(bar, __ATOMIC_RELAXED, __HIP_MEMORY_SCOPE_AGENT) < target) {
            __builtin_amdgcn_s_sleep(2);
        }
    }
    __syncthreads();
    __threadfence();   // acquire (L2 invalidate — weights live in VGPRs, so cheap)
}

// Attention LSTM for step t: weights passed BY VALUE (pinned registers).
__device__ __forceinline__ void attn_lstm_phase(
    const DecArgs& A, float* ws, float* s_in, float* s_part,
    int tid, int kg, int gate, int k16, int r, int blk, int t, int wp, int rp,
    float4 wa0, float4 wa1, float4 wa2, float4 wa3, float4 wa4, float4 wa5) {
    const int sid4 = (kg * 16 + k16) * 4;
    float xa0 = 0.f, xa1 = 0.f, xa2 = 0.f, xa3 = 0.f;
    if (tid < 64) {
        int b = tid >> 2, u = tid & 3;
        const float* xa = ws + OFF_XA + (size_t)(t * 16 + b) * 4096;
        int j = blk * 4 + u;
        xa0 = xa[j]; xa1 = xa[1024 + j]; xa2 = xa[2048 + j]; xa3 = xa[3072 + j];
    }
    for (int g4 = 0; g4 < 4; ++g4) {
        __syncthreads();
#pragma unroll
        for (int bb4 = 0; bb4 < 4; ++bb4) {
            int b = g4 * 4 + bb4;
            const float* ctx = ws + OFF_CTX + rp * 8192 + b * 512;
            const float* ah  = ws + OFF_ATTNH + rp * 16384 + b * 1024;
            float* dst = s_in + bb4 * 1536;
            dst[tid] = (tid < 512) ? ctx[tid] : ah[tid - 512];
            if (tid < 512) dst[1024 + tid] = ah[512 + tid];
        }
        __syncthreads();
#pragma unroll
        for (int bb4 = 0; bb4 < 4; ++bb4) {
            const float* xp = s_in + bb4 * 1536 + sid4;
            float4 x0 = *(const float4*)(xp);
            float4 x1 = *(const float4*)(xp + 256);
            float4 x2 = *(const float4*)(xp + 512);
            float4 x3 = *(const float4*)(xp + 768);
            float4 x4 = *(const float4*)(xp + 1024);
            float4 x5 = *(const float4*)(xp + 1280);
            float a = dot4(wa0, x0) + dot4(wa1, x1) + dot4(wa2, x2)
                    + dot4(wa3, x3) + dot4(wa4, x4) + dot4(wa5, x5);
            a += __shfl_xor(a, 4);
            a += __shfl_xor(a, 8);
            a += __shfl_xor(a, 16);
            a += __shfl_xor(a, 32);
            if (k16 == 0) s_part[((g4 * 4 + bb4) * 16 + gate * 4 + r) * 4 + kg] = a;
        }
    }
    __syncthreads();
    if (tid < 64) {
        int b = tid >> 2, u = tid & 3;
        float G0 = xa0, G1 = xa1, G2 = xa2, G3 = xa3;
        const float* pp = s_part + b * 64 + u * 4;
#pragma unroll
        for (int k = 0; k < 4; k++) {
            G0 += pp[0 * 16 + k]; G1 += pp[1 * 16 + k];
            G2 += pp[2 * 16 + k]; G3 += pp[3 * 16 + k];
        }
        int j = blk * 4 + u;
        float ig = sigmf(G0), fg = sigmf(G1), gg = tanhfast(G2), og = sigmf(G3);
        float c = fg * ws[OFF_ATTNC + b * 1024 + j] + ig * gg;
        ws[OFF_ATTNC + b * 1024 + j] = c;
        ws[OFF_ATTNH + wp * 16384 + b * 1024 + j] = og * tanhfast(c);
    }
}

// Decoder LSTM for step t. Bias sums (step-invariant) passed in registers.
__device__ __forceinline__ void dec_lstm_phase(
    const DecArgs& A, float* ws, float* s_in, float* s_part,
    int tid, int kg, int gate, int k16, int r, int blk, int wp, int rp,
    float bs0, float bs1, float bs2, float bs3,
    float4 wd0, float4 wd1, float4 wd2, float4 wd3, float4 wd4,
    float4 wd5, float4 wd6, float4 wd7, float4 wd8, float4 wd9) {
    const int sid4 = (kg * 16 + k16) * 4;
    for (int g4 = 0; g4 < 4; ++g4) {
        __syncthreads();
#pragma unroll
        for (int bb4 = 0; bb4 < 4; ++bb4) {
            int b = g4 * 4 + bb4;
            const float* ah  = ws + OFF_ATTNH + wp * 16384 + b * 1024;
            const float* ctx = ws + OFF_CTX + wp * 8192 + b * 512;
            const float* dh  = ws + OFF_DECH + rp * 16384 + b * 1024;
            float* dst = s_in + bb4 * 2560;
            dst[tid] = ah[tid];
            dst[1024 + tid] = (tid < 512) ? ctx[tid] : dh[tid - 512];
            if (tid < 512) dst[2048 + tid] = dh[512 + tid];
        }
        __syncthreads();
#pragma unroll
        for (int bb4 = 0; bb4 < 4; ++bb4) {
            const float* xp = s_in + bb4 * 2560 + sid4;
            float a;
            {
                float4 x0 = *(const float4*)(xp);
                float4 x1 = *(const float4*)(xp + 256);
                float4 x2 = *(const float4*)(xp + 512);
                float4 x3 = *(const float4*)(xp + 768);
                float4 x4 = *(const float4*)(xp + 1024);
                a = dot4(wd0, x0) + dot4(wd1, x1) + dot4(wd2, x2)
                  + dot4(wd3, x3) + dot4(wd4, x4);
            }
            {
                float4 x5 = *(const float4*)(xp + 1280);
                float4 x6 = *(const float4*)(xp + 1536);
                float4 x7 = *(const float4*)(xp + 1792);
                float4 x8 = *(const float4*)(xp + 2048);
                float4 x9 = *(const float4*)(xp + 2304);
                a += dot4(wd5, x5) + dot4(wd6, x6) + dot4(wd7, x7)
                   + dot4(wd8, x8) + dot4(wd9, x9);
            }
            a += __shfl_xor(a, 4);
            a += __shfl_xor(a, 8);
            a += __shfl_xor(a, 16);
            a += __shfl_xor(a, 32);
            if (k16 == 0) s_part[((g4 * 4 + bb4) * 16 + gate * 4 + r) * 4 + kg] = a;
        }
    }
    __syncthreads();
    if (tid < 64) {
        int b = tid >> 2, u = tid & 3;
        float G0 = bs0, G1 = bs1, G2 = bs2, G3 = bs3;
        const float* pp = s_part + b * 64 + u * 4;
#pragma unroll
        for (int k = 0; k < 4; k++) {
            G0 += pp[0 * 16 + k]; G1 += pp[1 * 16 + k];
            G2 += pp[2 * 16 + k]; G3 += pp[3 * 16 + k];
        }
        int j = blk * 4 + u;
        float ig = sigmf(G0), fg = sigmf(G1), gg = tanhfast(G2), og = sigmf(G3);
        float c = fg * ws[OFF_DECC + b * 1024 + j] + ig * gg;
        ws[OFF_DECC + b * 1024 + j] = c;
        ws[OFF_DECH + wp * 16384 + b * 1024 + j] = og * tanhfast(c);
    }
}

// __launch_bounds__(1024, 4): 16-wave block, VGPR cap 128, 1 block/CU.
__global__ void __launch_bounds__(1024, 4) decoder_main(DecArgs A) {
    const int tid = threadIdx.x;
    const int wv = tid >> 6;
    const int lane = tid & 63;
    const int blk = blockIdx.x;
    float* ws = A.ws;
    unsigned* bar = (unsigned*)(ws + OFF_BAR);

    // LDS
    __shared__ alignas(16) float s_in[10240];   // 40KB input staging (4 batches)
    __shared__ float s_part[1024];              // [16b][4gate][4unit][4kg]
    __shared__ float s_ah[1024];
    __shared__ float s_loc[128 * 33];
    __shared__ float s_cw[62 * 32];             // conv weights, [k][f]
    __shared__ float s_dw[128 * 33];            // dense weights, [a][f] padded
    __shared__ float s_pq[128];
    __shared__ float s_ev[128];
    __shared__ float s_aw2[128];
    __shared__ float s_awl[128];
    __shared__ float s_awcl[128];
    __shared__ float s_ep[1024];
    __shared__ float s_red[2];

    // thread layout for LSTM phases: wave = kg*4+gate ; lane = k16*4+r
    const int kg = wv >> 2;
    const int gate = wv & 3;
    const int k16 = lane >> 2;
    const int r = lane & 3;
    const int sid4 = (kg * 16 + k16) * 4;
    const int jrow = blk * 4 + r;
    const int arow = gate * 1024 + jrow;

    // ---- register-resident weights: loaded once, PINNED in VGPRs ----
    float4 wa0, wa1, wa2, wa3, wa4, wa5;         // attn: [ctx(512) | ah(1024)]
    {
        const float* wih = A.arnn_wih + (size_t)arow * 768 + 256;
        const float* whh = A.arnn_whh + (size_t)arow * 1024;
        wa0 = *(const float4*)(wih + 0 * 256 + sid4);
        wa1 = *(const float4*)(wih + 1 * 256 + sid4);
        wa2 = *(const float4*)(whh + 0 * 256 + sid4);
        wa3 = *(const float4*)(whh + 1 * 256 + sid4);
        wa4 = *(const float4*)(whh + 2 * 256 + sid4);
        wa5 = *(const float4*)(whh + 3 * 256 + sid4);
    }
    float4 wd0, wd1, wd2, wd3, wd4, wd5, wd6, wd7, wd8, wd9;  // dec: [ah|ctx|dh]
    {
        const float* wih = A.drnn_wih + (size_t)arow * 1536;
        const float* whh = A.drnn_whh + (size_t)arow * 1024;
        wd0 = *(const float4*)(wih + 0 * 256 + sid4);
        wd1 = *(const float4*)(wih + 1 * 256 + sid4);
        wd2 = *(const float4*)(wih + 2 * 256 + sid4);
        wd3 = *(const float4*)(wih + 3 * 256 + sid4);
        wd4 = *(const float4*)(wih + 4 * 256 + sid4);
        wd5 = *(const float4*)(wih + 5 * 256 + sid4);
        wd6 = *(const float4*)(whh + 0 * 256 + sid4);
        wd7 = *(const float4*)(whh + 1 * 256 + sid4);
        wd8 = *(const float4*)(whh + 2 * 256 + sid4);
        wd9 = *(const float4*)(whh + 3 * 256 + sid4);
    }
    PIN4(wa0); PIN4(wa1); PIN4(wa2); PIN4(wa3); PIN4(wa4); PIN4(wa5);
    PIN4(wd0); PIN4(wd1); PIN4(wd2); PIN4(wd3); PIN4(wd4);
    PIN4(wd5); PIN4(wd6); PIN4(wd7); PIN4(wd8); PIN4(wd9);

    // step-invariant decoder bias sums (finalize threads only), pinned
    float bs0 = 0.f, bs1 = 0.f, bs2 = 0.f, bs3 = 0.f;
    if (tid < 64) {
        int j = blk * 4 + (tid & 3);
        bs0 = A.drnn_bih[j] + A.drnn_bhh[j];
        bs1 = A.drnn_bih[1024 + j] + A.drnn_bhh[1024 + j];
        bs2 = A.drnn_bih[2048 + j] + A.drnn_bhh[2048 + j];
        bs3 = A.drnn_bih[3072 + j] + A.drnn_bhh[3072 + j];
    }
    asm volatile("" : "+v"(bs0), "+v"(bs1), "+v"(bs2), "+v"(bs3));

    // stage small attention weights in LDS (attention blocks only)
    if (blk < 16) {
        for (int i = tid; i < 62 * 32; i += 1024) {
            int k = i >> 5, f = i & 31;
            s_cw[k * 32 + f] = A.conv_w[f * 62 + k];
        }
        for (int i = tid; i < 128 * 32; i += 1024) {
            int a = i >> 5, f = i & 31;
            s_dw[a * 33 + f] = A.dense_w[a * 32 + f];
        }
    }

    auto attention = [&](int t, int wpar, int rpar) {
        const int b = blk;
        s_ah[tid] = ws[OFF_ATTNH + wpar * 16384 + b * 1024 + tid];
        if (tid < 128) {
            s_awl[tid] = ws[OFF_AW + rpar * 2048 + b * 128 + tid];
            s_awcl[tid] = ws[OFF_AWC + rpar * 2048 + b * 128 + tid];
        }
        __syncthreads();
        for (int idx = tid; idx < 4096; idx += 1024) {
            int f = idx >> 7, tt = idx & 127;
            float s = 0.f;
#pragma unroll 1
            for (int k = 0; k < 31; k++) {
                int j = tt + k - 15;
                float c0 = s_cw[k * 32 + f];
                float c1 = s_cw[(31 + k) * 32 + f];
                if (j >= 0 && j < 128) s += c0 * s_awl[j] + c1 * s_awcl[j];
            }
            s_loc[tt * 33 + f] = s;
        }
        {
#pragma unroll 1
            for (int ii = 0; ii < 8; ii++) {
                int a = wv * 8 + ii;
                const float* qw = A.query_w + a * 1024;
                float s = 0.f;
#pragma unroll
                for (int q = 0; q < 4; q++) {
                    int k = q * 256 + lane * 4;
                    float4 h4 = *reinterpret_cast<const float4*>(&s_ah[k]);
                    float4 w4 = *reinterpret_cast<const float4*>(&qw[k]);
                    s += dot4(h4, w4);
                }
#pragma unroll
                for (int off = 1; off < 64; off <<= 1) s += __shfl_xor(s, off);
                if (lane == 0) s_pq[a] = s;
            }
        }
        __syncthreads();
        {
            int tt = tid >> 3, sl = tid & 7;
            float part = 0.f;
#pragma unroll 1
            for (int i = 0; i < 16; i++) {
                int a = i * 8 + sl;
                float lp = 0.f;
                for (int f = 0; f < 32; f++) lp += s_loc[tt * 33 + f] * s_dw[a * 33 + f];
                float arg = s_pq[a] + lp + ws[OFF_PM + (b * 128 + tt) * 128 + a];
                part += A.v_w[a] * tanhfast(arg);
            }
            s_ep[tid] = part;
        }
        __syncthreads();
        int ml = A.memlen[b];
        if (tid < 128) {
            float s = 0.f;
#pragma unroll
            for (int q = 0; q < 8; q++) s += s_ep[tid * 8 + q];
            if (tid >= ml) s = -1e30f;
            s_ev[tid] = s;
        }
        __syncthreads();
        if (wv == 0) {
            float m = fmaxf(s_ev[lane], s_ev[lane + 64]);
#pragma unroll
            for (int off = 1; off < 64; off <<= 1) m = fmaxf(m, __shfl_xor(m, off));
            if (lane == 0) s_red[0] = m;
        }
        __syncthreads();
        if (tid < 128) s_aw2[tid] = __expf(s_ev[tid] - s_red[0]);
        __syncthreads();
        if (wv == 0) {
            float s = s_aw2[lane] + s_aw2[lane + 64];
#pragma unroll
            for (int off = 1; off < 64; off <<= 1) s += __shfl_xor(s, off);
            if (lane == 0) s_red[1] = 1.f / s;
        }
        __syncthreads();
        if (tid < 128) {
            float val = s_aw2[tid] * s_red[1];
            s_aw2[tid] = val;
            ws[OFF_AW + wpar * 2048 + b * 128 + tid] = val;
            ws[OFF_AWC + wpar * 2048 + b * 128 + tid] = s_awcl[tid] + val;
            A.out[165888 + b * 16384 + t * 128 + tid] = val;  // alignments
        }
        __syncthreads();
        if (tid < 512) {
            const float* mb = A.memory + (size_t)b * 65536 + tid;
            float acc = 0.f;
#pragma unroll 8
            for (int tt2 = 0; tt2 < 128; tt2++) acc += s_aw2[tt2] * mb[tt2 * 512];
            ws[OFF_CTX + wpar * 8192 + b * 512 + tid] = acc;
        }
    };

    auto eout = [&](int tdone) {
        int widx = (blk - 16) * 16 + wv;
        if (widx >= 1296) return;
        int ppar = tdone & 1;
        int b; const float* wrow; float bias; float* dst;
        if (widx < 1280) {
            b = widx / 80; int m = widx % 80;
            wrow = A.proj_w + m * 1536; bias = A.proj_b[m];
            dst = A.out + (size_t)(b * 80 + m) * 128 + tdone;
        } else {
            b = widx - 1280;
            wrow = A.gate_w; bias = A.gate_b[0];
            dst = A.out + 163840 + b * 128 + tdone;
        }
        const float* h1p = ws + OFF_DECH + ppar * 16384 + b * 1024;
        const float* c1p = ws + OFF_CTX + ppar * 8192 + b * 512;
        float s = 0.f;
#pragma unroll 1
        for (int q = 0; q < 6; q++) {
            int k = q * 256 + lane * 4;
            float4 w4 = *reinterpret_cast<const float4*>(&wrow[k]);
            float4 h4;
            if (k < 1024) h4 = *reinterpret_cast<const float4*>(&h1p[k]);
            else h4 = *reinterpret_cast<const float4*>(&c1p[k - 1024]);
            s += dot4(w4, h4);
        }
#pragma unroll
        for (int off = 1; off < 64; off <<= 1) s += __shfl_xor(s, off);
        if (lane == 0) *dst = s + bias;
    };

    unsigned bt = 0;

    // P1(0): attn LSTM for t=0 (reads zeroed state)
    attn_lstm_phase(A, ws, s_in, s_part, tid, kg, gate, k16, r, blk, 0, 0, 1,
                    wa0, wa1, wa2, wa3, wa4, wa5);
    bt += 256; gridbar(bar, bt);

    for (int t = 0; t < 128; t++) {
        int wpar = t & 1, rpar = wpar ^ 1;
        if (blk < 16) attention(t, wpar, rpar);
        else if (t >= 1) eout(t - 1);
        bt += 256; gridbar(bar, bt);
        // dec LSTM(t), then attn LSTM(t+1) — independent of dec(t), no barrier
        dec_lstm_phase(A, ws, s_in, s_part, tid, kg, gate, k16, r, blk, wpar, rpar,
                       bs0, bs1, bs2, bs3,
                       wd0, wd1, wd2, wd3, wd4, wd5, wd6, wd7, wd8, wd9);
        if (t + 1 < 128) {
            attn_lstm_phase(A, ws, s_in, s_part, tid, kg, gate, k16, r, blk,
                            t + 1, rpar, wpar, wa0, wa1, wa2, wa3, wa4, wa5);
        }
        bt += 256; gridbar(bar, bt);
    }
    if (blk >= 16) eout(127);
}

// ---------------- launcher ----------------

extern "C" void kernel_launch(void* const* d_in, const int* in_sizes, int n_in,
                              void* d_out, int out_size, void* d_ws, size_t ws_size,
                              hipStream_t stream) {
    (void)in_sizes; (void)n_in; (void)out_size; (void)ws_size;
    const float* memory    = (const float*)d_in[0];
    const float* mels      = (const float*)d_in[1];
    const int*   memlen    = (const int*)d_in[2];
    const float* prenet_w1 = (const float*)d_in[3];
    const float* prenet_w2 = (const float*)d_in[4];
    const float* arnn_wih  = (const float*)d_in[5];
    const float* arnn_whh  = (const float*)d_in[6];
    const float* arnn_bih  = (const float*)d_in[7];
    const float* arnn_bhh  = (const float*)d_in[8];
    const float* query_w   = (const float*)d_in[9];
    const float* memory_w  = (const float*)d_in[10];
    const float* v_w       = (const float*)d_in[11];
    const float* conv_w    = (const float*)d_in[12];
    const float* dense_w   = (const float*)d_in[13];
    const float* drnn_wih  = (const float*)d_in[14];
    const float* drnn_whh  = (const float*)d_in[15];
    const float* drnn_bih  = (const float*)d_in[16];
    const float* drnn_bhh  = (const float*)d_in[17];
    const float* proj_w    = (const float*)d_in[18];
    const float* proj_b    = (const float*)d_in[19];
    const float* gate_w    = (const float*)d_in[20];
    const float* gate_b    = (const float*)d_in[21];
    float* ws = (float*)d_ws;
    float* out = (float*)d_out;

    // zero recurrent state + barrier counter (ws is poisoned 0xAA each call)
    hipMemsetAsync(ws + OFF_ATTNH, 0, (STATE_FLOATS + 16) * sizeof(float), stream);

    build_decin<<<dim3(160), dim3(1024), 0, stream>>>(mels, ws + OFF_DECIN);
    gemm_kernel<<<dim3(4, 32), dim3(256), 0, stream>>>(ws + OFF_DECIN, 80, prenet_w1, 80,
                                                       ws + OFF_H1, 256, 2048, 256, 80,
                                                       nullptr, nullptr, 1);
    gemm_kernel<<<dim3(4, 32), dim3(256), 0, stream>>>(ws + OFF_H1, 256, prenet_w2, 256,
                                                       ws + OFF_X, 256, 2048, 256, 256,
                                                       nullptr, nullptr, 1);
    gemm_kernel<<<dim3(64, 32), dim3(256), 0, stream>>>(ws + OFF_X, 256, arnn_wih, 768,
                                                        ws + OFF_XA, 4096, 2048, 4096, 256,
                                                        arnn_bih, arnn_bhh, 0);
    gemm_kernel<<<dim3(2, 32), dim3(256), 0, stream>>>(memory, 512, memory_w, 512,
                                                       ws + OFF_PM, 128, 2048, 128, 512,
                                                       nullptr, nullptr, 0);

    DecArgs a;
    a.memory = memory; a.memlen = memlen;
    a.arnn_wih = arnn_wih; a.arnn_whh = arnn_whh;
    a.drnn_wih = drnn_wih; a.drnn_whh = drnn_whh;
    a.drnn_bih = drnn_bih; a.drnn_bhh = drnn_bhh;
    a.query_w = query_w; a.v_w = v_w;
    a.conv_w = conv_w; a.dense_w = dense_w;
    a.proj_w = proj_w; a.proj_b = proj_b;
    a.gate_w = gate_w; a.gate_b = gate_b;
    a.ws = ws; a.out = out;
    void* kargs[] = { &a };
    hipLaunchCooperativeKernel((const void*)decoder_main, dim3(256), dim3(1024),
                               kargs, 0, stream);
}